// Round 3
// baseline (2443.816 us; speedup 1.0000x reference)
//
#include <hip/hip_runtime.h>
#include <hip/hip_bf16.h>

// GPR-GNN forward on MI355X, f32 throughout.
// R3: (a) feature-chunked propagation: h stored [chunk=8][N][16], gridDim.y =
//     chunk -> per-phase gather working set 3.2MB fits per-XCD L2 (4MB).
//     One wave per (node,chunk), 4-edge ILP, packed (src,w) int2 edges.
// (b) k_mlp2 rewritten: W2 in LDS (wave-uniform broadcast reads), Z staged in
//     LDS k-chunks, 10 acc/lane, fused log_softmax via LDS logit exchange.

#define NFEAT 128
#define HID   256
#define NCLS  40
#define KHOPS 10
#define CHUNK 16
#define NCH   (NFEAT / CHUNK)   // 8

// ---- storage probe: int64 values < 2^31 have all-zero odd 32-bit words ----
__global__ void k_detect64(const unsigned int* __restrict__ raw, int* __restrict__ flag) {
  __shared__ int any;
  int t = threadIdx.x;
  if (t == 0) any = 0;
  __syncthreads();
  if (raw[2 * t + 1] != 0u) any = 1;   // benign race: all writers store 1
  __syncthreads();
  if (t == 0) flag[0] = (any == 0) ? 1 : 0;   // 1 => int64 storage
}

__global__ void k_zero(int* __restrict__ p, int n) {
  int i = blockIdx.x * blockDim.x + threadIdx.x;
  if (i < n) p[i] = 0;
}

__global__ void k_count(const int* __restrict__ ei32, const long long* __restrict__ ei64,
                        int E, int N, int* __restrict__ cnt, const int* __restrict__ flag) {
  int e = blockIdx.x * blockDim.x + threadIdx.x;
  if (e >= E) return;
  int dst = flag[0] ? (int)ei64[(size_t)E + e] : ei32[(size_t)E + e];
  if ((unsigned)dst < (unsigned)N) atomicAdd(&cnt[dst], 1);
}

// single 1024-thread block: exclusive scan -> row_start[0..N], cursors, dinv.
__global__ void k_scan(const int* __restrict__ cnt, int* __restrict__ row_start,
                       int* __restrict__ cursor, float* __restrict__ dinv, int N) {
  __shared__ int wsum[16];
  __shared__ int carry;
  int tid = threadIdx.x;
  int lane = tid & 63, wid = tid >> 6;
  if (tid == 0) carry = 0;
  __syncthreads();
  for (int base = 0; base < N; base += 1024) {
    int idx = base + tid;
    int v = (idx < N) ? cnt[idx] : 0;
    int x = v;
    #pragma unroll
    for (int off = 1; off < 64; off <<= 1) {
      int t = __shfl_up(x, off);
      if (lane >= off) x += t;
    }
    if (lane == 63) wsum[wid] = x;
    __syncthreads();
    if (wid == 0) {
      int s = (lane < 16) ? wsum[lane] : 0;
      #pragma unroll
      for (int off = 1; off < 16; off <<= 1) {
        int t = __shfl_up(s, off);
        if (lane >= off) s += t;
      }
      if (lane < 16) wsum[lane] = s;
    }
    __syncthreads();
    int woff = wid ? wsum[wid - 1] : 0;
    int excl = x - v + woff;
    int c = carry;
    if (idx < N) {
      int rs = c + excl;
      row_start[idx] = rs;
      cursor[idx] = rs;
      dinv[idx] = rsqrtf((float)(v + 1));
    }
    __syncthreads();
    if (tid == 0) carry = c + wsum[15];
    __syncthreads();
  }
  if (tid == 0) row_start[N] = carry;
}

__global__ void k_fill(const int* __restrict__ ei32, const long long* __restrict__ ei64,
                       int E, int N, const float* __restrict__ dinv,
                       int* __restrict__ cursor, int2* __restrict__ csr,
                       const int* __restrict__ flag) {
  int e = blockIdx.x * blockDim.x + threadIdx.x;
  if (e >= E) return;
  int src, dst;
  if (flag[0]) { src = (int)ei64[e]; dst = (int)ei64[(size_t)E + e]; }
  else         { src = ei32[e];      dst = ei32[(size_t)E + e]; }
  if ((unsigned)src >= (unsigned)N || (unsigned)dst >= (unsigned)N) return;
  int p = atomicAdd(&cursor[dst], 1);
  float w = dinv[src] * dinv[dst];
  csr[p] = make_int2(src, __float_as_int(w));
}

// x row-major -> h chunk-major [c][node][16]; hidden init = temp[0]*x.
__global__ void k_init_h(const float* __restrict__ x, const float* __restrict__ temp,
                         float* __restrict__ h, float* __restrict__ hidden, int N) {
  int i = blockIdx.x * blockDim.x + threadIdx.x;
  if (i >= N * NFEAT) return;
  int node = i >> 7, f = i & 127;
  int c = f >> 4, ff = f & 15;
  size_t idx = ((size_t)c * N + node) * CHUNK + ff;
  float v = x[i];
  h[idx] = v;
  hidden[idx] = temp[0] * v;
}

// One wave per (node, chunk). lane = e*16+f: 4 edges in flight per iteration,
// 64B gather per edge from the 3.2MB per-chunk h slab (L2-resident).
__global__ __launch_bounds__(256) void k_prop(
    const float* __restrict__ h, float* __restrict__ h_new, float* __restrict__ hidden,
    const int* __restrict__ row_start, const int2* __restrict__ csr,
    const float* __restrict__ dinv, const float* __restrict__ temp,
    int k, int N, int write_h) {
  int wid = threadIdx.x >> 6;
  int lane = threadIdx.x & 63;
  int node = blockIdx.x * 4 + wid;
  if (node >= N) return;
  int c = blockIdx.y;
  int f = lane & 15;
  int e = lane >> 4;
  size_t cbase = (size_t)c * N * CHUNK;
  int s = row_start[node], en = row_start[node + 1];
  float acc = 0.f;
  for (int p = s + e; p < en; p += 4) {
    int2 ed = csr[p];                         // 8B broadcast per 16-lane group
    acc += __int_as_float(ed.y) * h[cbase + (size_t)ed.x * CHUNK + f];
  }
  acc += __shfl_xor(acc, 16);
  acc += __shfl_xor(acc, 32);
  if (lane < 16) {
    float di = dinv[node];
    size_t idx = cbase + (size_t)node * CHUNK + f;
    float total = acc + di * di * h[idx];     // self-loop term
    if (write_h) h_new[idx] = total;
    hidden[idx] += temp[k + 1] * total;
  }
}

// hidden(chunk-major, K=128) @ W1(128x256) + b1, relu -> Z(Mx256 row-major).
__global__ __launch_bounds__(256) void k_gemm1(
    const float* __restrict__ A, const float* __restrict__ W1,
    const float* __restrict__ b1, float* __restrict__ Z, int M) {
  __shared__ float As[64][66];   // K-major: As[k][m]
  __shared__ float Bs[64][66];   // K-major: Bs[k][n]
  int tid = threadIdx.x;
  int m0 = blockIdx.x * 64, n0 = blockIdx.y * 64;
  int tm = (tid >> 4) << 2;
  int tn = (tid & 15) << 2;
  float acc[4][4] = {};
  for (int kk = 0; kk < NFEAT; kk += 64) {
    for (int idx = tid; idx < 64 * 64; idx += 256) {
      int m = idx >> 6, ka = idx & 63;
      int gr = m0 + m;
      int kg = kk + ka;
      As[ka][m] = (gr < M) ? A[((size_t)(kg >> 4) * M + gr) * CHUNK + (kg & 15)] : 0.f;
      Bs[ka][m] = W1[(size_t)kg * HID + n0 + m];   // reuse (ka,m) as (k,n)
    }
    __syncthreads();
    #pragma unroll 8
    for (int k = 0; k < 64; ++k) {
      float2 a0 = *(const float2*)&As[k][tm];
      float2 a1 = *(const float2*)&As[k][tm + 2];
      float2 bx = *(const float2*)&Bs[k][tn];
      float2 by = *(const float2*)&Bs[k][tn + 2];
      float a4[4] = {a0.x, a0.y, a1.x, a1.y};
      float b4[4] = {bx.x, bx.y, by.x, by.y};
      #pragma unroll
      for (int i = 0; i < 4; ++i)
        #pragma unroll
        for (int j = 0; j < 4; ++j)
          acc[i][j] += a4[i] * b4[j];
    }
    __syncthreads();
  }
  float bias[4];
  #pragma unroll
  for (int j = 0; j < 4; ++j) bias[j] = b1[n0 + tn + j];
  #pragma unroll
  for (int i = 0; i < 4; ++i) {
    int row = m0 + tm + i;
    if (row < M) {
      float4 o;
      o.x = fmaxf(acc[i][0] + bias[0], 0.f);
      o.y = fmaxf(acc[i][1] + bias[1], 0.f);
      o.z = fmaxf(acc[i][2] + bias[2], 0.f);
      o.w = fmaxf(acc[i][3] + bias[3], 0.f);
      *(float4*)&Z[(size_t)row * HID + n0 + tn] = o;
    }
  }
}

// Z(Mx256) @ W2(256x40) + b2 -> log_softmax -> out. Block = 64 nodes.
// Wave q owns classes [q*10, q*10+10): W2 reads are wave-uniform LDS broadcasts.
__global__ __launch_bounds__(256) void k_mlp2(
    const float* __restrict__ z1, const float* __restrict__ W2,
    const float* __restrict__ b2, float* __restrict__ out, int N) {
  __shared__ __align__(16) float W2g[4][HID][12];  // [q][k][j<10], rows 48B-aligned
  __shared__ __align__(16) float Zs[64][36];       // 32-k chunk, stride 36: b128 conflict-free
  int tid = threadIdx.x;
  int q = tid >> 6, lane = tid & 63;
  for (int idx = tid; idx < 4 * HID * 10; idx += 256) {
    int qq = idx / (HID * 10);
    int rem = idx - qq * (HID * 10);
    int k = rem / 10, j = rem - k * 10;
    W2g[qq][k][j] = W2[k * NCLS + qq * 10 + j];
  }
  int n0 = blockIdx.x * 64;
  int node = n0 + lane;
  float acc[10];
  #pragma unroll
  for (int j = 0; j < 10; ++j) acc[j] = b2[q * 10 + j];
  for (int kk = 0; kk < HID; kk += 32) {
    __syncthreads();   // protects previous Zs reads; also orders W2g staging (1st iter)
    for (int idx = tid; idx < 64 * 8; idx += 256) {
      int nn = idx >> 3;
      int kq = (idx & 7) * 4;
      int gn = n0 + nn;
      float4 v = make_float4(0.f, 0.f, 0.f, 0.f);
      if (gn < N) v = *(const float4*)&z1[(size_t)gn * HID + kk + kq];
      *(float4*)&Zs[nn][kq] = v;
    }
    __syncthreads();
    #pragma unroll
    for (int k4 = 0; k4 < 32; k4 += 4) {
      float4 zv = *(const float4*)&Zs[lane][k4];
      float zz[4] = {zv.x, zv.y, zv.z, zv.w};
      #pragma unroll
      for (int t = 0; t < 4; ++t) {
        int k = kk + k4 + t;
        float4 w0 = *(const float4*)&W2g[q][k][0];
        float4 w1 = *(const float4*)&W2g[q][k][4];
        float2 w2 = *(const float2*)&W2g[q][k][8];
        acc[0] += zz[t] * w0.x;  acc[1] += zz[t] * w0.y;
        acc[2] += zz[t] * w0.z;  acc[3] += zz[t] * w0.w;
        acc[4] += zz[t] * w1.x;  acc[5] += zz[t] * w1.y;
        acc[6] += zz[t] * w1.z;  acc[7] += zz[t] * w1.w;
        acc[8] += zz[t] * w2.x;  acc[9] += zz[t] * w2.y;
      }
    }
  }
  // exchange logits through LDS (W2g region is dead now), then log_softmax
  __syncthreads();
  float* logits = &W2g[0][0][0];   // needs 64*40 = 2560 floats, fits easily
  #pragma unroll
  for (int j = 0; j < 10; ++j) logits[lane * NCLS + q * 10 + j] = acc[j];
  __syncthreads();
  int nl = tid >> 2;        // node local 0..63
  int r = tid & 3;          // quad: 4 threads per node, 10 classes each
  const float* lg = &logits[nl * NCLS + r * 10];
  float l10[10];
  float m = -3.4e38f;
  #pragma unroll
  for (int j = 0; j < 10; ++j) { l10[j] = lg[j]; m = fmaxf(m, l10[j]); }
  m = fmaxf(m, __shfl_xor(m, 1));
  m = fmaxf(m, __shfl_xor(m, 2));
  float s = 0.f;
  #pragma unroll
  for (int j = 0; j < 10; ++j) s += __expf(l10[j] - m);
  s += __shfl_xor(s, 1);
  s += __shfl_xor(s, 2);
  float lse = m + __logf(s);
  int gnode = n0 + nl;
  if (gnode < N) {
    #pragma unroll
    for (int j = 0; j < 10; ++j) out[(size_t)gnode * NCLS + r * 10 + j] = l10[j] - lse;
  }
}

extern "C" void kernel_launch(void* const* d_in, const int* in_sizes, int n_in,
                              void* d_out, int out_size, void* d_ws, size_t ws_size,
                              hipStream_t stream) {
  const float*     x    = (const float*)d_in[0];
  const int*       ei32 = (const int*)d_in[1];
  const long long* ei64 = (const long long*)d_in[1];
  const float*     temp = (const float*)d_in[2];
  const float*     W1   = (const float*)d_in[3];
  const float*     b1   = (const float*)d_in[4];
  const float*     W2   = (const float*)d_in[5];
  const float*     b2   = (const float*)d_in[6];
  float* out = (float*)d_out;

  int N = in_sizes[0] / NFEAT;   // 50000
  int E = in_sizes[1] / 2;       // 800000

  char* w = (char*)d_ws;
  auto carve = [&](size_t bytes) -> void* {
    void* p = (void*)w;
    w += (bytes + 255) & ~(size_t)255;
    return p;
  };
  int*   flag      = (int*)  carve(4);
  int*   cnt       = (int*)  carve((size_t)N * 4);
  int*   row_start = (int*)  carve(((size_t)N + 1) * 4);
  int*   cursor    = (int*)  carve((size_t)N * 4);
  float* dinv      = (float*)carve((size_t)N * 4);
  int2*  csr       = (int2*) carve((size_t)E * 8);
  float* h_a       = (float*)carve((size_t)N * NFEAT * 4);
  float* h_b       = (float*)carve((size_t)N * NFEAT * 4);
  float* hidden    = (float*)carve((size_t)N * NFEAT * 4);
  float* z1        = h_a;   // h ping-pong region is dead after propagation

  k_detect64<<<1, 256, 0, stream>>>((const unsigned int*)d_in[1], flag);
  k_zero<<<(N + 255) / 256, 256, 0, stream>>>(cnt, N);
  k_count<<<(E + 255) / 256, 256, 0, stream>>>(ei32, ei64, E, N, cnt, flag);
  k_scan<<<1, 1024, 0, stream>>>(cnt, row_start, cursor, dinv, N);
  k_fill<<<(E + 255) / 256, 256, 0, stream>>>(ei32, ei64, E, N, dinv, cursor, csr, flag);
  k_init_h<<<(N * NFEAT + 255) / 256, 256, 0, stream>>>(x, temp, h_a, hidden, N);

  float* hc = h_a;
  float* hn = h_b;
  for (int k = 0; k < KHOPS; ++k) {
    k_prop<<<dim3((N + 3) / 4, NCH), 256, 0, stream>>>(
        hc, hn, hidden, row_start, csr, dinv, temp, k, N, (k < KHOPS - 1) ? 1 : 0);
    float* t2 = hc; hc = hn; hn = t2;
  }

  k_gemm1<<<dim3((N + 63) / 64, HID / 64), 256, 0, stream>>>(hidden, W1, b1, z1, N);
  k_mlp2<<<(N + 63) / 64, 256, 0, stream>>>(z1, W2, b2, out, N);
}

// Round 4
// 708.139 us; speedup vs baseline: 3.4510x; 3.4510x over previous
//
#include <hip/hip_runtime.h>
#include <hip/hip_bf16.h>

// GPR-GNN forward on MI355X, f32 accumulate / bf16 h-storage.
// R4: revert R3's chunking (latency-bound regression). Row-major bf16 h rows:
// one 256B wave-gather per edge, 8 edges in flight per wave, scalar CSR loads.

#define NFEAT 128
#define HID   256
#define NCLS  40
#define KHOPS 10

__device__ __forceinline__ float blo(unsigned g) { return __uint_as_float(g << 16); }
__device__ __forceinline__ float bhi(unsigned g) { return __uint_as_float(g & 0xffff0000u); }
__device__ __forceinline__ unsigned f2bf(float x) {          // RNE bf16, returns low 16
  unsigned u = __float_as_uint(x);
  return (u + 0x7fffu + ((u >> 16) & 1u)) >> 16;
}
__device__ __forceinline__ unsigned bpack(float a, float b) {
  return f2bf(a) | (f2bf(b) << 16);
}

// ---- storage probe: int64 values < 2^31 have all-zero odd 32-bit words ----
__global__ void k_detect64(const unsigned int* __restrict__ raw, int* __restrict__ flag) {
  __shared__ int any;
  int t = threadIdx.x;
  if (t == 0) any = 0;
  __syncthreads();
  if (raw[2 * t + 1] != 0u) any = 1;
  __syncthreads();
  if (t == 0) flag[0] = (any == 0) ? 1 : 0;   // 1 => int64 storage
}

__global__ void k_zero(int* __restrict__ p, int n) {
  int i = blockIdx.x * blockDim.x + threadIdx.x;
  if (i < n) p[i] = 0;
}

__global__ void k_count(const int* __restrict__ ei32, const long long* __restrict__ ei64,
                        int E, int N, int* __restrict__ cnt, const int* __restrict__ flag) {
  int e = blockIdx.x * blockDim.x + threadIdx.x;
  if (e >= E) return;
  int dst = flag[0] ? (int)ei64[(size_t)E + e] : ei32[(size_t)E + e];
  if ((unsigned)dst < (unsigned)N) atomicAdd(&cnt[dst], 1);
}

// single 1024-thread block: exclusive scan -> row_start[0..N], cursors, dinv.
__global__ void k_scan(const int* __restrict__ cnt, int* __restrict__ row_start,
                       int* __restrict__ cursor, float* __restrict__ dinv, int N) {
  __shared__ int wsum[16];
  __shared__ int carry;
  int tid = threadIdx.x;
  int lane = tid & 63, wid = tid >> 6;
  if (tid == 0) carry = 0;
  __syncthreads();
  for (int base = 0; base < N; base += 1024) {
    int idx = base + tid;
    int v = (idx < N) ? cnt[idx] : 0;
    int x = v;
    #pragma unroll
    for (int off = 1; off < 64; off <<= 1) {
      int t = __shfl_up(x, off);
      if (lane >= off) x += t;
    }
    if (lane == 63) wsum[wid] = x;
    __syncthreads();
    if (wid == 0) {
      int s = (lane < 16) ? wsum[lane] : 0;
      #pragma unroll
      for (int off = 1; off < 16; off <<= 1) {
        int t = __shfl_up(s, off);
        if (lane >= off) s += t;
      }
      if (lane < 16) wsum[lane] = s;
    }
    __syncthreads();
    int woff = wid ? wsum[wid - 1] : 0;
    int excl = x - v + woff;
    int c = carry;
    if (idx < N) {
      int rs = c + excl;
      row_start[idx] = rs;
      cursor[idx] = rs;
      dinv[idx] = rsqrtf((float)(v + 1));
    }
    __syncthreads();
    if (tid == 0) carry = c + wsum[15];
    __syncthreads();
  }
  if (tid == 0) row_start[N] = carry;
}

__global__ void k_fill(const int* __restrict__ ei32, const long long* __restrict__ ei64,
                       int E, int N, const float* __restrict__ dinv,
                       int* __restrict__ cursor, int2* __restrict__ csr,
                       const int* __restrict__ flag) {
  int e = blockIdx.x * blockDim.x + threadIdx.x;
  if (e >= E) return;
  int src, dst;
  if (flag[0]) { src = (int)ei64[e]; dst = (int)ei64[(size_t)E + e]; }
  else         { src = ei32[e];      dst = ei32[(size_t)E + e]; }
  if ((unsigned)src >= (unsigned)N || (unsigned)dst >= (unsigned)N) return;
  int p = atomicAdd(&cursor[dst], 1);
  float w = dinv[src] * dinv[dst];
  csr[p] = make_int2(src, __float_as_int(w));
}

// x (f32 row-major) -> h2 (bf16x2 packed, [node][64] uints); hidden = temp[0]*x.
__global__ void k_init_h(const float* __restrict__ x, const float* __restrict__ temp,
                         unsigned* __restrict__ h2, float* __restrict__ hidden, int N) {
  int i = blockIdx.x * blockDim.x + threadIdx.x;
  if (i >= N * 64) return;
  float2 xv = ((const float2*)x)[i];
  h2[i] = bpack(xv.x, xv.y);
  float t0 = temp[0];
  ((float2*)hidden)[i] = make_float2(t0 * xv.x, t0 * xv.y);
}

// One wave per node. lane f covers features 2f,2f+1 (one uint = full-row 256B
// wave gather). 8 edges in flight; CSR read via scalar loads (node is SGPR).
__global__ __launch_bounds__(256) void k_prop(
    const unsigned* __restrict__ h2, unsigned* __restrict__ hnew2,
    float* __restrict__ hidden,
    const int* __restrict__ row_start, const int2* __restrict__ csr,
    const float* __restrict__ dinv, const float* __restrict__ temp,
    int k, int N, int write_h) {
  int wid = __builtin_amdgcn_readfirstlane(threadIdx.x >> 6);
  int lane = threadIdx.x & 63;
  int node = blockIdx.x * 4 + wid;           // uniform (SGPR) per wave
  if (node >= N) return;
  int s = row_start[node], en = row_start[node + 1];
  float accL = 0.f, accH = 0.f;
  for (int p = s; p < en; p += 8) {
    unsigned g[8];
    float wt[8];
    #pragma unroll
    for (int j = 0; j < 8; ++j) {
      int pj = p + j;
      int2 e = csr[pj < en ? pj : s];        // clamped tail: dummy load, w=0
      wt[j] = (pj < en) ? __int_as_float(e.y) : 0.f;
      g[j] = h2[(size_t)e.x * 64 + lane];    // 256B row gather, 8 in flight
    }
    #pragma unroll
    for (int j = 0; j < 8; ++j) {
      accL += wt[j] * blo(g[j]);
      accH += wt[j] * bhi(g[j]);
    }
  }
  float di = dinv[node];
  unsigned gs = h2[(size_t)node * 64 + lane];
  float dd = di * di;
  accL += dd * blo(gs);                      // self-loop term
  accH += dd * bhi(gs);
  if (write_h) hnew2[(size_t)node * 64 + lane] = bpack(accL, accH);
  float tk = temp[k + 1];
  float2* hp = (float2*)(hidden + (size_t)node * NFEAT) + lane;
  float2 hv = *hp;
  hv.x += tk * accL;
  hv.y += tk * accH;
  *hp = hv;
}

// hidden (Mx128 f32 row-major) @ W1 (128x256) + b1, relu -> z1 (Mx256 bf16).
__global__ __launch_bounds__(256) void k_gemm1(
    const float* __restrict__ A, const float* __restrict__ W1,
    const float* __restrict__ b1, unsigned short* __restrict__ z1, int M) {
  __shared__ float As[64][66];   // K-major: As[k][m]
  __shared__ float Bs[64][66];   // K-major: Bs[k][n]
  int tid = threadIdx.x;
  int m0 = blockIdx.x * 64, n0 = blockIdx.y * 64;
  int tm = (tid >> 4) << 2;
  int tn = (tid & 15) << 2;
  float acc[4][4] = {};
  for (int kk = 0; kk < NFEAT; kk += 64) {
    for (int idx = tid; idx < 64 * 64; idx += 256) {
      int m = idx >> 6, ka = idx & 63;       // ka fastest: coalesced
      int gr = m0 + m;
      As[ka][m] = (gr < M) ? A[(size_t)gr * NFEAT + kk + ka] : 0.f;
      Bs[ka][m] = W1[(size_t)(kk + ka) * HID + n0 + m];  // (ka,m) as (k,n), n fastest
    }
    __syncthreads();
    #pragma unroll 8
    for (int k = 0; k < 64; ++k) {
      float2 a0 = *(const float2*)&As[k][tm];
      float2 a1 = *(const float2*)&As[k][tm + 2];
      float2 bx = *(const float2*)&Bs[k][tn];
      float2 by = *(const float2*)&Bs[k][tn + 2];
      float a4[4] = {a0.x, a0.y, a1.x, a1.y};
      float b4[4] = {bx.x, bx.y, by.x, by.y};
      #pragma unroll
      for (int i = 0; i < 4; ++i)
        #pragma unroll
        for (int j = 0; j < 4; ++j)
          acc[i][j] += a4[i] * b4[j];
    }
    __syncthreads();
  }
  float bias[4];
  #pragma unroll
  for (int j = 0; j < 4; ++j) bias[j] = b1[n0 + tn + j];
  #pragma unroll
  for (int i = 0; i < 4; ++i) {
    int row = m0 + tm + i;
    if (row < M) {
      float o0 = fmaxf(acc[i][0] + bias[0], 0.f);
      float o1 = fmaxf(acc[i][1] + bias[1], 0.f);
      float o2 = fmaxf(acc[i][2] + bias[2], 0.f);
      float o3 = fmaxf(acc[i][3] + bias[3], 0.f);
      uint2 pk = make_uint2(bpack(o0, o1), bpack(o2, o3));
      *(uint2*)&z1[(size_t)row * HID + n0 + tn] = pk;
    }
  }
}

// z1 (Mx256 bf16) @ W2 (256x40) + b2 -> log_softmax -> out f32. Block = 64 nodes.
// Wave q owns classes [q*10, q*10+10): W2 reads are wave-uniform LDS broadcasts.
__global__ __launch_bounds__(256) void k_mlp2(
    const unsigned short* __restrict__ z1, const float* __restrict__ W2,
    const float* __restrict__ b2, float* __restrict__ out, int N) {
  __shared__ __align__(16) float W2g[4][HID][12];  // [q][k][j<10]
  __shared__ __align__(16) float Zs[64][36];       // 32-k chunk
  int tid = threadIdx.x;
  int q = tid >> 6, lane = tid & 63;
  for (int idx = tid; idx < 4 * HID * 10; idx += 256) {
    int qq = idx / (HID * 10);
    int rem = idx - qq * (HID * 10);
    int k = rem / 10, j = rem - k * 10;
    W2g[qq][k][j] = W2[k * NCLS + qq * 10 + j];
  }
  int n0 = blockIdx.x * 64;
  float acc[10];
  #pragma unroll
  for (int j = 0; j < 10; ++j) acc[j] = b2[q * 10 + j];
  for (int kk = 0; kk < HID; kk += 32) {
    __syncthreads();   // protects previous Zs reads; orders W2g staging (1st iter)
    {
      int nn = tid >> 2;          // 4 threads per node, 8 bf16 (16B) each
      int part = tid & 3;
      int gn = n0 + nn;
      uint4 v = make_uint4(0u, 0u, 0u, 0u);
      if (gn < N) v = *(const uint4*)&z1[(size_t)gn * HID + kk + part * 8];
      float4 f0 = make_float4(blo(v.x), bhi(v.x), blo(v.y), bhi(v.y));
      float4 f1 = make_float4(blo(v.z), bhi(v.z), blo(v.w), bhi(v.w));
      *(float4*)&Zs[nn][part * 8] = f0;
      *(float4*)&Zs[nn][part * 8 + 4] = f1;
    }
    __syncthreads();
    #pragma unroll
    for (int k4 = 0; k4 < 32; k4 += 4) {
      float4 zv = *(const float4*)&Zs[lane][k4];
      float zz[4] = {zv.x, zv.y, zv.z, zv.w};
      #pragma unroll
      for (int t = 0; t < 4; ++t) {
        int k = kk + k4 + t;
        float4 w0 = *(const float4*)&W2g[q][k][0];
        float4 w1 = *(const float4*)&W2g[q][k][4];
        float2 w2 = *(const float2*)&W2g[q][k][8];
        acc[0] += zz[t] * w0.x;  acc[1] += zz[t] * w0.y;
        acc[2] += zz[t] * w0.z;  acc[3] += zz[t] * w0.w;
        acc[4] += zz[t] * w1.x;  acc[5] += zz[t] * w1.y;
        acc[6] += zz[t] * w1.z;  acc[7] += zz[t] * w1.w;
        acc[8] += zz[t] * w2.x;  acc[9] += zz[t] * w2.y;
      }
    }
  }
  __syncthreads();
  float* logits = &W2g[0][0][0];   // W2g region dead now; 64*40 floats
  #pragma unroll
  for (int j = 0; j < 10; ++j) logits[lane * NCLS + q * 10 + j] = acc[j];
  __syncthreads();
  int nl = tid >> 2;
  int r = tid & 3;
  const float* lg = &logits[nl * NCLS + r * 10];
  float l10[10];
  float m = -3.4e38f;
  #pragma unroll
  for (int j = 0; j < 10; ++j) { l10[j] = lg[j]; m = fmaxf(m, l10[j]); }
  m = fmaxf(m, __shfl_xor(m, 1));
  m = fmaxf(m, __shfl_xor(m, 2));
  float s = 0.f;
  #pragma unroll
  for (int j = 0; j < 10; ++j) s += __expf(l10[j] - m);
  s += __shfl_xor(s, 1);
  s += __shfl_xor(s, 2);
  float lse = m + __logf(s);
  int gnode = n0 + nl;
  if (gnode < N) {
    #pragma unroll
    for (int j = 0; j < 10; ++j) out[(size_t)gnode * NCLS + r * 10 + j] = l10[j] - lse;
  }
}

extern "C" void kernel_launch(void* const* d_in, const int* in_sizes, int n_in,
                              void* d_out, int out_size, void* d_ws, size_t ws_size,
                              hipStream_t stream) {
  const float*     x    = (const float*)d_in[0];
  const int*       ei32 = (const int*)d_in[1];
  const long long* ei64 = (const long long*)d_in[1];
  const float*     temp = (const float*)d_in[2];
  const float*     W1   = (const float*)d_in[3];
  const float*     b1   = (const float*)d_in[4];
  const float*     W2   = (const float*)d_in[5];
  const float*     b2   = (const float*)d_in[6];
  float* out = (float*)d_out;

  int N = in_sizes[0] / NFEAT;   // 50000
  int E = in_sizes[1] / 2;       // 800000

  // workspace carve (~84 MB total, matches the R2-proven budget)
  char* w = (char*)d_ws;
  auto carve = [&](size_t bytes) -> void* {
    void* p = (void*)w;
    w += (bytes + 255) & ~(size_t)255;
    return p;
  };
  int*      flag      = (int*)     carve(4);
  int*      cnt       = (int*)     carve((size_t)N * 4);
  int*      row_start = (int*)     carve(((size_t)N + 1) * 4);
  int*      cursor    = (int*)     carve((size_t)N * 4);
  float*    dinv      = (float*)   carve((size_t)N * 4);
  int2*     csr       = (int2*)    carve((size_t)E * 8);
  unsigned* h_a       = (unsigned*)carve((size_t)N * 64 * 4);   // bf16x2 rows
  unsigned* h_b       = (unsigned*)carve((size_t)N * 64 * 4);
  float*    hidden    = (float*)   carve((size_t)N * NFEAT * 4);
  unsigned short* z1  = (unsigned short*)carve((size_t)N * HID * 2);

  k_detect64<<<1, 256, 0, stream>>>((const unsigned int*)d_in[1], flag);
  k_zero<<<(N + 255) / 256, 256, 0, stream>>>(cnt, N);
  k_count<<<(E + 255) / 256, 256, 0, stream>>>(ei32, ei64, E, N, cnt, flag);
  k_scan<<<1, 1024, 0, stream>>>(cnt, row_start, cursor, dinv, N);
  k_fill<<<(E + 255) / 256, 256, 0, stream>>>(ei32, ei64, E, N, dinv, cursor, csr, flag);
  k_init_h<<<(N * 64 + 255) / 256, 256, 0, stream>>>(x, temp, h_a, hidden, N);

  unsigned* hc = h_a;
  unsigned* hn = h_b;
  for (int k = 0; k < KHOPS; ++k) {
    k_prop<<<(N + 3) / 4, 256, 0, stream>>>(
        hc, hn, hidden, row_start, csr, dinv, temp, k, N, (k < KHOPS - 1) ? 1 : 0);
    unsigned* t2 = hc; hc = hn; hn = t2;
  }

  k_gemm1<<<dim3((N + 63) / 64, HID / 64), 256, 0, stream>>>(hidden, W1, b1, z1, N);
  k_mlp2<<<(N + 63) / 64, 256, 0, stream>>>(z1, W2, b2, out, N);
}

// Round 5
// 644.806 us; speedup vs baseline: 3.7900x; 1.0982x over previous
//
#include <hip/hip_runtime.h>
#include <hip/hip_bf16.h>

// GPR-GNN forward on MI355X.
// R5: (a) k_gemm1 rewritten as bf16 MFMA (16x16x32), A = bf16 hidden produced
//     by the fused final prop hop (writes hidden as bf16 into the dead h slot,
//     removing one 25.6MB f32 RMW). Conflict-free frag reads, LDS-repacked
//     coalesced z1 stores. (b) k_prop gather unroll 8 -> 16 (avg degree = 16).

#define NFEAT 128
#define HID   256
#define NCLS  40
#define KHOPS 10

typedef __attribute__((ext_vector_type(8))) short short8;
typedef __attribute__((ext_vector_type(4))) float floatx4;

__device__ __forceinline__ float blo(unsigned g) { return __uint_as_float(g << 16); }
__device__ __forceinline__ float bhi(unsigned g) { return __uint_as_float(g & 0xffff0000u); }
__device__ __forceinline__ unsigned f2bf(float x) {          // RNE bf16 -> low 16
  unsigned u = __float_as_uint(x);
  return (u + 0x7fffu + ((u >> 16) & 1u)) >> 16;
}
__device__ __forceinline__ unsigned bpack(float a, float b) {
  return f2bf(a) | (f2bf(b) << 16);
}

// ---- storage probe: int64 values < 2^31 have all-zero odd 32-bit words ----
__global__ void k_detect64(const unsigned int* __restrict__ raw, int* __restrict__ flag) {
  __shared__ int any;
  int t = threadIdx.x;
  if (t == 0) any = 0;
  __syncthreads();
  if (raw[2 * t + 1] != 0u) any = 1;
  __syncthreads();
  if (t == 0) flag[0] = (any == 0) ? 1 : 0;   // 1 => int64 storage
}

__global__ void k_zero(int* __restrict__ p, int n) {
  int i = blockIdx.x * blockDim.x + threadIdx.x;
  if (i < n) p[i] = 0;
}

__global__ void k_count(const int* __restrict__ ei32, const long long* __restrict__ ei64,
                        int E, int N, int* __restrict__ cnt, const int* __restrict__ flag) {
  int e = blockIdx.x * blockDim.x + threadIdx.x;
  if (e >= E) return;
  int dst = flag[0] ? (int)ei64[(size_t)E + e] : ei32[(size_t)E + e];
  if ((unsigned)dst < (unsigned)N) atomicAdd(&cnt[dst], 1);
}

// single 1024-thread block: exclusive scan -> row_start[0..N], cursors, dinv.
__global__ void k_scan(const int* __restrict__ cnt, int* __restrict__ row_start,
                       int* __restrict__ cursor, float* __restrict__ dinv, int N) {
  __shared__ int wsum[16];
  __shared__ int carry;
  int tid = threadIdx.x;
  int lane = tid & 63, wid = tid >> 6;
  if (tid == 0) carry = 0;
  __syncthreads();
  for (int base = 0; base < N; base += 1024) {
    int idx = base + tid;
    int v = (idx < N) ? cnt[idx] : 0;
    int x = v;
    #pragma unroll
    for (int off = 1; off < 64; off <<= 1) {
      int t = __shfl_up(x, off);
      if (lane >= off) x += t;
    }
    if (lane == 63) wsum[wid] = x;
    __syncthreads();
    if (wid == 0) {
      int s = (lane < 16) ? wsum[lane] : 0;
      #pragma unroll
      for (int off = 1; off < 16; off <<= 1) {
        int t = __shfl_up(s, off);
        if (lane >= off) s += t;
      }
      if (lane < 16) wsum[lane] = s;
    }
    __syncthreads();
    int woff = wid ? wsum[wid - 1] : 0;
    int excl = x - v + woff;
    int c = carry;
    if (idx < N) {
      int rs = c + excl;
      row_start[idx] = rs;
      cursor[idx] = rs;
      dinv[idx] = rsqrtf((float)(v + 1));
    }
    __syncthreads();
    if (tid == 0) carry = c + wsum[15];
    __syncthreads();
  }
  if (tid == 0) row_start[N] = carry;
}

__global__ void k_fill(const int* __restrict__ ei32, const long long* __restrict__ ei64,
                       int E, int N, const float* __restrict__ dinv,
                       int* __restrict__ cursor, int2* __restrict__ csr,
                       const int* __restrict__ flag) {
  int e = blockIdx.x * blockDim.x + threadIdx.x;
  if (e >= E) return;
  int src, dst;
  if (flag[0]) { src = (int)ei64[e]; dst = (int)ei64[(size_t)E + e]; }
  else         { src = ei32[e];      dst = ei32[(size_t)E + e]; }
  if ((unsigned)src >= (unsigned)N || (unsigned)dst >= (unsigned)N) return;
  int p = atomicAdd(&cursor[dst], 1);
  float w = dinv[src] * dinv[dst];
  csr[p] = make_int2(src, __float_as_int(w));
}

// x (f32 row-major) -> h2 (bf16x2 packed, [node][64] uints); hidden = temp[0]*x.
__global__ void k_init_h(const float* __restrict__ x, const float* __restrict__ temp,
                         unsigned* __restrict__ h2, float* __restrict__ hidden, int N) {
  int i = blockIdx.x * blockDim.x + threadIdx.x;
  if (i >= N * 64) return;
  float2 xv = ((const float2*)x)[i];
  h2[i] = bpack(xv.x, xv.y);
  float t0 = temp[0];
  ((float2*)hidden)[i] = make_float2(t0 * xv.x, t0 * xv.y);
}

// One wave per node; lane covers features 2f,2f+1. 16 edges in flight.
// mode 0: write hnew2 (bf16) + RMW hidden (f32).
// mode 1 (final hop): read hidden f32, write hid_bf16 = hidden + t*total.
__global__ __launch_bounds__(256) void k_prop(
    const unsigned* __restrict__ h2, unsigned* __restrict__ hnew2,
    float* __restrict__ hidden,
    const int* __restrict__ row_start, const int2* __restrict__ csr,
    const float* __restrict__ dinv, const float* __restrict__ temp,
    int k, int N, int mode) {
  int wid = __builtin_amdgcn_readfirstlane(threadIdx.x >> 6);
  int lane = threadIdx.x & 63;
  int node = blockIdx.x * 4 + wid;           // uniform (SGPR) per wave
  if (node >= N) return;
  int s = row_start[node], en = row_start[node + 1];
  float accL = 0.f, accH = 0.f;
  for (int p = s; p < en; p += 16) {
    unsigned g[16];
    float wt[16];
    #pragma unroll
    for (int j = 0; j < 16; ++j) {
      int pj = p + j;
      int2 e = csr[pj < en ? pj : s];        // clamped tail: broadcast dummy
      wt[j] = (pj < en) ? __int_as_float(e.y) : 0.f;
      g[j] = h2[(size_t)e.x * 64 + lane];    // 256B row gather, 16 in flight
    }
    #pragma unroll
    for (int j = 0; j < 16; ++j) {
      accL += wt[j] * blo(g[j]);
      accH += wt[j] * bhi(g[j]);
    }
  }
  float di = dinv[node];
  unsigned gs = h2[(size_t)node * 64 + lane];
  float dd = di * di;
  accL += dd * blo(gs);                      // self-loop term
  accH += dd * bhi(gs);
  float tk = temp[k + 1];
  float2* hp = (float2*)(hidden + (size_t)node * NFEAT) + lane;
  float2 hv = *hp;
  hv.x += tk * accL;
  hv.y += tk * accH;
  if (mode == 0) {
    hnew2[(size_t)node * 64 + lane] = bpack(accL, accH);
    *hp = hv;
  } else {
    hnew2[(size_t)node * 64 + lane] = bpack(hv.x, hv.y);   // final hidden, bf16
  }
}

// hidden_bf16 (Mx128) @ W1 (128x256 f32) + b1, relu -> z1 (Mx256 bf16).
// MFMA 16x16x32 bf16. Block = 4 waves, 64M x 128N tile (grid.y = N half).
__global__ __launch_bounds__(256) void k_gemm1(
    const unsigned short* __restrict__ Ab, const float* __restrict__ W1,
    const float* __restrict__ b1, unsigned short* __restrict__ z1, int M) {
  __shared__ unsigned short As[64][136];   // m-major, k contig, +8 pad (272B rows)
  __shared__ unsigned short Bs[16][128][8]; // [k>>3][n][k&7]: frag = ds_read_b128
  int tid = threadIdx.x;
  int m0 = blockIdx.x * 64;
  int n0 = blockIdx.y * 128;
  // A staging: direct 16B copies (rows are k-contiguous bf16)
  for (int idx = tid; idx < 64 * 16; idx += 256) {
    int m = idx >> 4, c = idx & 15;
    int row = m0 + m; if (row >= M) row = M - 1;
    uint4 v = *(const uint4*)(Ab + (size_t)row * NFEAT + c * 8);
    *(uint4*)&As[m][c * 8] = v;
  }
  // B staging: f32 -> bf16, transpose k-major -> [k8][n][8]
  for (int idx = tid; idx < 128 * 128; idx += 256) {
    int k = idx >> 7, n = idx & 127;       // consecutive tid -> consecutive n
    Bs[k >> 3][n][k & 7] = (unsigned short)f2bf(W1[(size_t)k * HID + n0 + n]);
  }
  __syncthreads();
  int lane = tid & 63;
  int q = lane >> 4, r16 = lane & 15;
  int nw = (tid >> 6) * 32;                // wave's n-offset within the half
  floatx4 acc[4][2] = {};
  #pragma unroll
  for (int step = 0; step < 4; ++step) {   // K = 4 x 32
    int k0 = step * 32;
    short8 a[4], b[2];
    #pragma unroll
    for (int i = 0; i < 4; ++i)
      a[i] = *(const short8*)&As[i * 16 + r16][k0 + q * 8];
    #pragma unroll
    for (int j = 0; j < 2; ++j)
      b[j] = *(const short8*)&Bs[step * 4 + q][nw + j * 16 + r16][0];
    #pragma unroll
    for (int i = 0; i < 4; ++i)
      #pragma unroll
      for (int j = 0; j < 2; ++j)
        acc[i][j] = __builtin_amdgcn_mfma_f32_16x16x32_bf16(a[i], b[j], acc[i][j], 0, 0, 0);
  }
  // epilogue: bias + relu, repack via LDS (reuse As) for coalesced stores
  __syncthreads();
  unsigned short* Zs = &As[0][0];          // [64][136] ushort, n<128 used
  #pragma unroll
  for (int j = 0; j < 2; ++j) {
    int n = nw + j * 16 + r16;
    float bias = b1[n0 + n];
    #pragma unroll
    for (int i = 0; i < 4; ++i) {
      #pragma unroll
      for (int r = 0; r < 4; ++r) {
        int m = i * 16 + q * 4 + r;
        float v = fmaxf(acc[i][j][r] + bias, 0.f);
        Zs[m * 136 + n] = (unsigned short)f2bf(v);
      }
    }
  }
  __syncthreads();
  for (int idx = tid; idx < 64 * 16; idx += 256) {
    int m = idx >> 4, c = idx & 15;
    int row = m0 + m;
    if (row < M) {
      uint4 v = *(const uint4*)&Zs[m * 136 + c * 8];
      *(uint4*)(z1 + (size_t)row * HID + n0 + c * 8) = v;
    }
  }
}

// z1 (Mx256 bf16) @ W2 (256x40) + b2 -> log_softmax -> out f32. Block = 64 nodes.
__global__ __launch_bounds__(256) void k_mlp2(
    const unsigned short* __restrict__ z1, const float* __restrict__ W2,
    const float* __restrict__ b2, float* __restrict__ out, int N) {
  __shared__ __align__(16) float W2g[4][HID][12];  // [q][k][j<10]
  __shared__ __align__(16) float Zs[64][36];       // 32-k chunk
  int tid = threadIdx.x;
  int q = tid >> 6, lane = tid & 63;
  for (int idx = tid; idx < 4 * HID * 10; idx += 256) {
    int qq = idx / (HID * 10);
    int rem = idx - qq * (HID * 10);
    int k = rem / 10, j = rem - k * 10;
    W2g[qq][k][j] = W2[k * NCLS + qq * 10 + j];
  }
  int n0 = blockIdx.x * 64;
  float acc[10];
  #pragma unroll
  for (int j = 0; j < 10; ++j) acc[j] = b2[q * 10 + j];
  for (int kk = 0; kk < HID; kk += 32) {
    __syncthreads();
    {
      int nn = tid >> 2;          // 4 threads per node, 8 bf16 (16B) each
      int part = tid & 3;
      int gn = n0 + nn;
      uint4 v = make_uint4(0u, 0u, 0u, 0u);
      if (gn < N) v = *(const uint4*)&z1[(size_t)gn * HID + kk + part * 8];
      float4 f0 = make_float4(blo(v.x), bhi(v.x), blo(v.y), bhi(v.y));
      float4 f1 = make_float4(blo(v.z), bhi(v.z), blo(v.w), bhi(v.w));
      *(float4*)&Zs[nn][part * 8] = f0;
      *(float4*)&Zs[nn][part * 8 + 4] = f1;
    }
    __syncthreads();
    #pragma unroll
    for (int k4 = 0; k4 < 32; k4 += 4) {
      float4 zv = *(const float4*)&Zs[lane][k4];
      float zz[4] = {zv.x, zv.y, zv.z, zv.w};
      #pragma unroll
      for (int t = 0; t < 4; ++t) {
        int k = kk + k4 + t;
        float4 w0 = *(const float4*)&W2g[q][k][0];
        float4 w1 = *(const float4*)&W2g[q][k][4];
        float2 w2 = *(const float2*)&W2g[q][k][8];
        acc[0] += zz[t] * w0.x;  acc[1] += zz[t] * w0.y;
        acc[2] += zz[t] * w0.z;  acc[3] += zz[t] * w0.w;
        acc[4] += zz[t] * w1.x;  acc[5] += zz[t] * w1.y;
        acc[6] += zz[t] * w1.z;  acc[7] += zz[t] * w1.w;
        acc[8] += zz[t] * w2.x;  acc[9] += zz[t] * w2.y;
      }
    }
  }
  __syncthreads();
  float* logits = &W2g[0][0][0];
  #pragma unroll
  for (int j = 0; j < 10; ++j) logits[lane * NCLS + q * 10 + j] = acc[j];
  __syncthreads();
  int nl = tid >> 2;
  int r = tid & 3;
  const float* lg = &logits[nl * NCLS + r * 10];
  float l10[10];
  float m = -3.4e38f;
  #pragma unroll
  for (int j = 0; j < 10; ++j) { l10[j] = lg[j]; m = fmaxf(m, l10[j]); }
  m = fmaxf(m, __shfl_xor(m, 1));
  m = fmaxf(m, __shfl_xor(m, 2));
  float s = 0.f;
  #pragma unroll
  for (int j = 0; j < 10; ++j) s += __expf(l10[j] - m);
  s += __shfl_xor(s, 1);
  s += __shfl_xor(s, 2);
  float lse = m + __logf(s);
  int gnode = n0 + nl;
  if (gnode < N) {
    #pragma unroll
    for (int j = 0; j < 10; ++j) out[(size_t)gnode * NCLS + r * 10 + j] = l10[j] - lse;
  }
}

extern "C" void kernel_launch(void* const* d_in, const int* in_sizes, int n_in,
                              void* d_out, int out_size, void* d_ws, size_t ws_size,
                              hipStream_t stream) {
  const float*     x    = (const float*)d_in[0];
  const int*       ei32 = (const int*)d_in[1];
  const long long* ei64 = (const long long*)d_in[1];
  const float*     temp = (const float*)d_in[2];
  const float*     W1   = (const float*)d_in[3];
  const float*     b1   = (const float*)d_in[4];
  const float*     W2   = (const float*)d_in[5];
  const float*     b2   = (const float*)d_in[6];
  float* out = (float*)d_out;

  int N = in_sizes[0] / NFEAT;   // 50000
  int E = in_sizes[1] / 2;       // 800000

  // workspace carve (~84 MB, matches the R2-proven budget)
  char* w = (char*)d_ws;
  auto carve = [&](size_t bytes) -> void* {
    void* p = (void*)w;
    w += (bytes + 255) & ~(size_t)255;
    return p;
  };
  int*      flag      = (int*)     carve(4);
  int*      cnt       = (int*)     carve((size_t)N * 4);
  int*      row_start = (int*)     carve(((size_t)N + 1) * 4);
  int*      cursor    = (int*)     carve((size_t)N * 4);
  float*    dinv      = (float*)   carve((size_t)N * 4);
  int2*     csr       = (int2*)    carve((size_t)E * 8);
  unsigned* h_a       = (unsigned*)carve((size_t)N * 64 * 4);   // bf16x2 rows
  unsigned* h_b       = (unsigned*)carve((size_t)N * 64 * 4);
  float*    hidden    = (float*)   carve((size_t)N * NFEAT * 4);
  unsigned short* z1  = (unsigned short*)hidden;   // f32 hidden dead after final prop

  k_detect64<<<1, 256, 0, stream>>>((const unsigned int*)d_in[1], flag);
  k_zero<<<(N + 255) / 256, 256, 0, stream>>>(cnt, N);
  k_count<<<(E + 255) / 256, 256, 0, stream>>>(ei32, ei64, E, N, cnt, flag);
  k_scan<<<1, 1024, 0, stream>>>(cnt, row_start, cursor, dinv, N);
  k_fill<<<(E + 255) / 256, 256, 0, stream>>>(ei32, ei64, E, N, dinv, cursor, csr, flag);
  k_init_h<<<(N * 64 + 255) / 256, 256, 0, stream>>>(x, temp, h_a, hidden, N);

  unsigned* hc = h_a;
  unsigned* hn = h_b;
  for (int k = 0; k < KHOPS - 1; ++k) {
    k_prop<<<(N + 3) / 4, 256, 0, stream>>>(
        hc, hn, hidden, row_start, csr, dinv, temp, k, N, 0);
    unsigned* t2 = hc; hc = hn; hn = t2;
  }
  // final hop: writes bf16 hidden into hn (f32 hidden read one last time)
  k_prop<<<(N + 3) / 4, 256, 0, stream>>>(
      hc, hn, hidden, row_start, csr, dinv, temp, KHOPS - 1, N, 1);
  unsigned short* hidden_bf16 = (unsigned short*)hn;

  k_gemm1<<<dim3((N + 63) / 64, 2), 256, 0, stream>>>(hidden_bf16, W1, b1, z1, N);
  k_mlp2<<<(N + 63) / 64, 256, 0, stream>>>(z1, W2, b2, out, N);
}

// Round 7
// 612.261 us; speedup vs baseline: 3.9915x; 1.0532x over previous
//
#include <hip/hip_runtime.h>
#include <hip/hip_bf16.h>
#include <hip/hip_cooperative_groups.h>

namespace cg = cooperative_groups;

// GPR-GNN forward on MI355X.
// R7: R6's cooperative persistent propagation, but defended: occupancy-query
// before launch, 962-block grid (margin under the 1024 co-residency cap),
// error-checked hipLaunchCooperativeKernel with a deterministic fallback to
// the proven R5 10-launch prop path. Both paths produce the same hid buffer.

#define NFEAT 128
#define HID   256
#define NCLS  40
#define KHOPS 10
#define PBLOCKS 962             // 3848 waves x NPW 13 = 50024 >= 50000
#define NPW     13

typedef __attribute__((ext_vector_type(8))) short short8;
typedef __attribute__((ext_vector_type(4))) float floatx4;

__device__ __forceinline__ float blo(unsigned g) { return __uint_as_float(g << 16); }
__device__ __forceinline__ float bhi(unsigned g) { return __uint_as_float(g & 0xffff0000u); }
__device__ __forceinline__ unsigned f2bf(float x) {          // RNE bf16 -> low 16
  unsigned u = __float_as_uint(x);
  return (u + 0x7fffu + ((u >> 16) & 1u)) >> 16;
}
__device__ __forceinline__ unsigned bpack(float a, float b) {
  return f2bf(a) | (f2bf(b) << 16);
}

// ---- storage probe: int64 values < 2^31 have all-zero odd 32-bit words ----
__global__ void k_detect64(const unsigned int* __restrict__ raw, int* __restrict__ flag) {
  __shared__ int any;
  int t = threadIdx.x;
  if (t == 0) any = 0;
  __syncthreads();
  if (raw[2 * t + 1] != 0u) any = 1;
  __syncthreads();
  if (t == 0) flag[0] = (any == 0) ? 1 : 0;   // 1 => int64 storage
}

__global__ void k_zero(int* __restrict__ p, int n) {
  int i = blockIdx.x * blockDim.x + threadIdx.x;
  if (i < n) p[i] = 0;
}

__global__ void k_count(const int* __restrict__ ei32, const long long* __restrict__ ei64,
                        int E, int N, int* __restrict__ cnt, const int* __restrict__ flag) {
  int e = blockIdx.x * blockDim.x + threadIdx.x;
  if (e >= E) return;
  int dst = flag[0] ? (int)ei64[(size_t)E + e] : ei32[(size_t)E + e];
  if ((unsigned)dst < (unsigned)N) atomicAdd(&cnt[dst], 1);
}

// ---- parallel scan: (a) per-1024-tile sums, (b) 1-wave scan of tile sums,
//      (c) per-tile scan + apply offsets -> row_start/cursor/dinv ----
__global__ __launch_bounds__(256) void k_scan_a(
    const int* __restrict__ cnt, int* __restrict__ bsum, int N) {
  int t = threadIdx.x;
  int base = blockIdx.x * 1024 + t * 4;
  int s = 0;
  if (base + 3 < N) {
    int4 v = *(const int4*)(cnt + base);
    s = v.x + v.y + v.z + v.w;
  } else {
    #pragma unroll
    for (int j = 0; j < 4; ++j) if (base + j < N) s += cnt[base + j];
  }
  #pragma unroll
  for (int off = 1; off < 64; off <<= 1) s += __shfl_xor(s, off);
  __shared__ int ws[4];
  if ((t & 63) == 0) ws[t >> 6] = s;
  __syncthreads();
  if (t == 0) bsum[blockIdx.x] = ws[0] + ws[1] + ws[2] + ws[3];
}

__global__ void k_scan_b(int* __restrict__ bsum, int* __restrict__ row_start,
                         int nblk, int N) {
  int t = threadIdx.x;                 // one wave (64 threads), nblk <= 64
  int v = (t < nblk) ? bsum[t] : 0;
  int x = v;
  #pragma unroll
  for (int off = 1; off < 64; off <<= 1) {
    int u = __shfl_up(x, off);
    if (t >= off) x += u;
  }
  if (t < nblk) bsum[t] = x - v;       // exclusive tile offsets
  if (t == 63) row_start[N] = x;       // grand total
}

__global__ __launch_bounds__(256) void k_scan_c(
    const int* __restrict__ cnt, const int* __restrict__ bsum,
    int* __restrict__ row_start, int* __restrict__ cursor,
    float* __restrict__ dinv, int N) {
  int t = threadIdx.x;
  int base = blockIdx.x * 1024 + t * 4;
  int v[4];
  if (base + 3 < N) {
    int4 q = *(const int4*)(cnt + base);
    v[0] = q.x; v[1] = q.y; v[2] = q.z; v[3] = q.w;
  } else {
    #pragma unroll
    for (int j = 0; j < 4; ++j) v[j] = (base + j < N) ? cnt[base + j] : 0;
  }
  int tsum = v[0] + v[1] + v[2] + v[3];
  int lane = t & 63, wv = t >> 6;
  int x = tsum;
  #pragma unroll
  for (int off = 1; off < 64; off <<= 1) {
    int u = __shfl_up(x, off);
    if (lane >= off) x += u;
  }
  __shared__ int ws[4];
  if (lane == 63) ws[wv] = x;
  __syncthreads();
  int woff = 0;
  #pragma unroll
  for (int j = 0; j < 4; ++j) if (j < wv) woff += ws[j];
  int run = x - tsum + woff + bsum[blockIdx.x];
  #pragma unroll
  for (int j = 0; j < 4; ++j) {
    int idx = base + j;
    if (idx < N) {
      row_start[idx] = run;
      cursor[idx] = run;
      dinv[idx] = rsqrtf((float)(v[j] + 1));
      run += v[j];
    }
  }
}

__global__ void k_fill(const int* __restrict__ ei32, const long long* __restrict__ ei64,
                       int E, int N, const float* __restrict__ dinv,
                       int* __restrict__ cursor, int2* __restrict__ csr,
                       const int* __restrict__ flag) {
  int e = blockIdx.x * blockDim.x + threadIdx.x;
  if (e >= E) return;
  int src, dst;
  if (flag[0]) { src = (int)ei64[e]; dst = (int)ei64[(size_t)E + e]; }
  else         { src = ei32[e];      dst = ei32[(size_t)E + e]; }
  if ((unsigned)src >= (unsigned)N || (unsigned)dst >= (unsigned)N) return;
  int p = atomicAdd(&cursor[dst], 1);
  float w = dinv[src] * dinv[dst];
  csr[p] = make_int2(src, __float_as_int(w));
}

// x (f32 row-major) -> h2 (bf16x2 packed, [node][64] uints)
__global__ void k_init_h(const float* __restrict__ x, unsigned* __restrict__ h2,
                         int total64) {
  int i = blockIdx.x * blockDim.x + threadIdx.x;
  if (i >= total64) return;
  float2 xv = ((const float2*)x)[i];
  h2[i] = bpack(xv.x, xv.y);
}

// fallback only: hidden_f32 = temp[0] * x
__global__ void k_init_hid32(const float* __restrict__ x, const float* __restrict__ temp,
                             float* __restrict__ hidden, int total64) {
  int i = blockIdx.x * blockDim.x + threadIdx.x;
  if (i >= total64) return;
  float2 xv = ((const float2*)x)[i];
  float t0 = temp[0];
  ((float2*)hidden)[i] = make_float2(t0 * xv.x, t0 * xv.y);
}

// Cooperative persistent propagation: all 10 hops in one launch.
// Wave owns NPW consecutive nodes; hidden accumulator lives in registers.
__global__ __launch_bounds__(256, 4) void k_prop_all(
    unsigned* __restrict__ h_a, unsigned* __restrict__ h_b,
    unsigned* __restrict__ hid_out,
    const int* __restrict__ row_start, const int2* __restrict__ csr,
    const float* __restrict__ dinv, const float* __restrict__ temp, int N) {
  cg::grid_group grid = cg::this_grid();
  int gwave = __builtin_amdgcn_readfirstlane(
      (int)((blockIdx.x * blockDim.x + threadIdx.x) >> 6));
  int lane = threadIdx.x & 63;
  int node0 = gwave * NPW;

  float hidL[NPW], hidH[NPW];
  float t0 = temp[0];
  #pragma unroll
  for (int i = 0; i < NPW; ++i) {
    int node = node0 + i;
    if (node < N) {
      unsigned g = h_a[(size_t)node * 64 + lane];
      hidL[i] = t0 * blo(g);
      hidH[i] = t0 * bhi(g);
    } else { hidL[i] = 0.f; hidH[i] = 0.f; }
  }

  const unsigned* hc = h_a;
  unsigned* hn = h_b;
  for (int k = 0; k < KHOPS; ++k) {
    float tk = temp[k + 1];
    #pragma unroll
    for (int i = 0; i < NPW; ++i) {          // full unroll: hid stays in VGPRs
      int node = node0 + i;
      if (node < N) {
        int s = row_start[node], en = row_start[node + 1];
        float accL = 0.f, accH = 0.f;
        for (int p = s; p < en; p += 16) {
          unsigned g[16];
          float wt[16];
          #pragma unroll
          for (int j = 0; j < 16; ++j) {
            int pj = p + j;
            int2 e = csr[pj < en ? pj : s];  // clamped tail: broadcast dummy
            wt[j] = (pj < en) ? __int_as_float(e.y) : 0.f;
            g[j] = hc[(size_t)e.x * 64 + lane];
          }
          #pragma unroll
          for (int j = 0; j < 16; ++j) {
            accL += wt[j] * blo(g[j]);
            accH += wt[j] * bhi(g[j]);
          }
        }
        float di = dinv[node];
        float dd = di * di;
        unsigned gs = hc[(size_t)node * 64 + lane];
        accL += dd * blo(gs);                // self-loop term
        accH += dd * bhi(gs);
        if (k < KHOPS - 1)
          hn[(size_t)node * 64 + lane] = bpack(accL, accH);
        hidL[i] += tk * accL;
        hidH[i] += tk * accH;
      }
    }
    __threadfence();                         // release hn writes (device scope)
    grid.sync();
    __threadfence();                         // acquire before reading peers' data
    const unsigned* t2 = hc; hc = hn; hn = (unsigned*)t2;
  }

  #pragma unroll
  for (int i = 0; i < NPW; ++i) {
    int node = node0 + i;
    if (node < N) hid_out[(size_t)node * 64 + lane] = bpack(hidL[i], hidH[i]);
  }
}

// Fallback single-hop prop (proven R5). mode 0: write hnew2 bf16 + RMW f32
// hidden. mode 1 (final hop): write hid_bf16 = hidden + t*total into hnew2.
__global__ __launch_bounds__(256) void k_prop(
    const unsigned* __restrict__ h2, unsigned* __restrict__ hnew2,
    float* __restrict__ hidden,
    const int* __restrict__ row_start, const int2* __restrict__ csr,
    const float* __restrict__ dinv, const float* __restrict__ temp,
    int k, int N, int mode) {
  int wid = __builtin_amdgcn_readfirstlane(threadIdx.x >> 6);
  int lane = threadIdx.x & 63;
  int node = blockIdx.x * 4 + wid;
  if (node >= N) return;
  int s = row_start[node], en = row_start[node + 1];
  float accL = 0.f, accH = 0.f;
  for (int p = s; p < en; p += 16) {
    unsigned g[16];
    float wt[16];
    #pragma unroll
    for (int j = 0; j < 16; ++j) {
      int pj = p + j;
      int2 e = csr[pj < en ? pj : s];
      wt[j] = (pj < en) ? __int_as_float(e.y) : 0.f;
      g[j] = h2[(size_t)e.x * 64 + lane];
    }
    #pragma unroll
    for (int j = 0; j < 16; ++j) {
      accL += wt[j] * blo(g[j]);
      accH += wt[j] * bhi(g[j]);
    }
  }
  float di = dinv[node];
  unsigned gs = h2[(size_t)node * 64 + lane];
  float dd = di * di;
  accL += dd * blo(gs);
  accH += dd * bhi(gs);
  float tk = temp[k + 1];
  float2* hp = (float2*)(hidden + (size_t)node * NFEAT) + lane;
  float2 hv = *hp;
  hv.x += tk * accL;
  hv.y += tk * accH;
  if (mode == 0) {
    hnew2[(size_t)node * 64 + lane] = bpack(accL, accH);
    *hp = hv;
  } else {
    hnew2[(size_t)node * 64 + lane] = bpack(hv.x, hv.y);
  }
}

// hidden_bf16 (Mx128) @ W1 (128x256 f32) + b1, relu -> z1 (Mx256 bf16).
__global__ __launch_bounds__(256) void k_gemm1(
    const unsigned short* __restrict__ Ab, const float* __restrict__ W1,
    const float* __restrict__ b1, unsigned short* __restrict__ z1, int M) {
  __shared__ unsigned short As[64][136];    // m-major, k contig, +8 pad
  __shared__ unsigned short Bs[16][128][8]; // [k>>3][n][k&7]: frag = ds_read_b128
  int tid = threadIdx.x;
  int m0 = blockIdx.x * 64;
  int n0 = blockIdx.y * 128;
  for (int idx = tid; idx < 64 * 16; idx += 256) {
    int m = idx >> 4, c = idx & 15;
    int row = m0 + m; if (row >= M) row = M - 1;
    uint4 v = *(const uint4*)(Ab + (size_t)row * NFEAT + c * 8);
    *(uint4*)&As[m][c * 8] = v;
  }
  for (int idx = tid; idx < 128 * 128; idx += 256) {
    int k = idx >> 7, n = idx & 127;
    Bs[k >> 3][n][k & 7] = (unsigned short)f2bf(W1[(size_t)k * HID + n0 + n]);
  }
  __syncthreads();
  int lane = tid & 63;
  int q = lane >> 4, r16 = lane & 15;
  int nw = (tid >> 6) * 32;
  floatx4 acc[4][2] = {};
  #pragma unroll
  for (int step = 0; step < 4; ++step) {
    int k0 = step * 32;
    short8 a[4], b[2];
    #pragma unroll
    for (int i = 0; i < 4; ++i)
      a[i] = *(const short8*)&As[i * 16 + r16][k0 + q * 8];
    #pragma unroll
    for (int j = 0; j < 2; ++j)
      b[j] = *(const short8*)&Bs[step * 4 + q][nw + j * 16 + r16][0];
    #pragma unroll
    for (int i = 0; i < 4; ++i)
      #pragma unroll
      for (int j = 0; j < 2; ++j)
        acc[i][j] = __builtin_amdgcn_mfma_f32_16x16x32_bf16(a[i], b[j], acc[i][j], 0, 0, 0);
  }
  __syncthreads();
  unsigned short* Zs = &As[0][0];
  #pragma unroll
  for (int j = 0; j < 2; ++j) {
    int n = nw + j * 16 + r16;
    float bias = b1[n0 + n];
    #pragma unroll
    for (int i = 0; i < 4; ++i) {
      #pragma unroll
      for (int r = 0; r < 4; ++r) {
        int m = i * 16 + q * 4 + r;
        float v = fmaxf(acc[i][j][r] + bias, 0.f);
        Zs[m * 136 + n] = (unsigned short)f2bf(v);
      }
    }
  }
  __syncthreads();
  for (int idx = tid; idx < 64 * 16; idx += 256) {
    int m = idx >> 4, c = idx & 15;
    int row = m0 + m;
    if (row < M) {
      uint4 v = *(const uint4*)&Zs[m * 136 + c * 8];
      *(uint4*)(z1 + (size_t)row * HID + n0 + c * 8) = v;
    }
  }
}

// z1 (Mx256 bf16) @ W2 (256x40) + b2 -> log_softmax -> out f32. Block = 64 nodes.
__global__ __launch_bounds__(256) void k_mlp2(
    const unsigned short* __restrict__ z1, const float* __restrict__ W2,
    const float* __restrict__ b2, float* __restrict__ out, int N) {
  __shared__ __align__(16) float W2g[4][HID][12];  // [q][k][j<10]
  __shared__ __align__(16) float Zs[64][36];       // 32-k chunk
  int tid = threadIdx.x;
  int q = tid >> 6, lane = tid & 63;
  for (int idx = tid; idx < 4 * HID * 10; idx += 256) {
    int qq = idx / (HID * 10);
    int rem = idx - qq * (HID * 10);
    int k = rem / 10, j = rem - k * 10;
    W2g[qq][k][j] = W2[k * NCLS + qq * 10 + j];
  }
  int n0 = blockIdx.x * 64;
  float acc[10];
  #pragma unroll
  for (int j = 0; j < 10; ++j) acc[j] = b2[q * 10 + j];
  for (int kk = 0; kk < HID; kk += 32) {
    __syncthreads();
    {
      int nn = tid >> 2;
      int part = tid & 3;
      int gn = n0 + nn;
      uint4 v = make_uint4(0u, 0u, 0u, 0u);
      if (gn < N) v = *(const uint4*)&z1[(size_t)gn * HID + kk + part * 8];
      float4 f0 = make_float4(blo(v.x), bhi(v.x), blo(v.y), bhi(v.y));
      float4 f1 = make_float4(blo(v.z), bhi(v.z), blo(v.w), bhi(v.w));
      *(float4*)&Zs[nn][part * 8] = f0;
      *(float4*)&Zs[nn][part * 8 + 4] = f1;
    }
    __syncthreads();
    #pragma unroll
    for (int k4 = 0; k4 < 32; k4 += 4) {
      float4 zv = *(const float4*)&Zs[lane][k4];
      float zz[4] = {zv.x, zv.y, zv.z, zv.w};
      #pragma unroll
      for (int t = 0; t < 4; ++t) {
        int k = kk + k4 + t;
        float4 w0 = *(const float4*)&W2g[q][k][0];
        float4 w1 = *(const float4*)&W2g[q][k][4];
        float2 w2 = *(const float2*)&W2g[q][k][8];
        acc[0] += zz[t] * w0.x;  acc[1] += zz[t] * w0.y;
        acc[2] += zz[t] * w0.z;  acc[3] += zz[t] * w0.w;
        acc[4] += zz[t] * w1.x;  acc[5] += zz[t] * w1.y;
        acc[6] += zz[t] * w1.z;  acc[7] += zz[t] * w1.w;
        acc[8] += zz[t] * w2.x;  acc[9] += zz[t] * w2.y;
      }
    }
  }
  __syncthreads();
  float* logits = &W2g[0][0][0];
  #pragma unroll
  for (int j = 0; j < 10; ++j) logits[lane * NCLS + q * 10 + j] = acc[j];
  __syncthreads();
  int nl = tid >> 2;
  int r = tid & 3;
  const float* lg = &logits[nl * NCLS + r * 10];
  float l10[10];
  float m = -3.4e38f;
  #pragma unroll
  for (int j = 0; j < 10; ++j) { l10[j] = lg[j]; m = fmaxf(m, l10[j]); }
  m = fmaxf(m, __shfl_xor(m, 1));
  m = fmaxf(m, __shfl_xor(m, 2));
  float s = 0.f;
  #pragma unroll
  for (int j = 0; j < 10; ++j) s += __expf(l10[j] - m);
  s += __shfl_xor(s, 1);
  s += __shfl_xor(s, 2);
  float lse = m + __logf(s);
  int gnode = n0 + nl;
  if (gnode < N) {
    #pragma unroll
    for (int j = 0; j < 10; ++j) out[(size_t)gnode * NCLS + r * 10 + j] = l10[j] - lse;
  }
}

extern "C" void kernel_launch(void* const* d_in, const int* in_sizes, int n_in,
                              void* d_out, int out_size, void* d_ws, size_t ws_size,
                              hipStream_t stream) {
  const float*     x    = (const float*)d_in[0];
  const int*       ei32 = (const int*)d_in[1];
  const long long* ei64 = (const long long*)d_in[1];
  const float*     temp = (const float*)d_in[2];
  const float*     W1   = (const float*)d_in[3];
  const float*     b1   = (const float*)d_in[4];
  const float*     W2   = (const float*)d_in[5];
  const float*     b2   = (const float*)d_in[6];
  float* out = (float*)d_out;

  int N = in_sizes[0] / NFEAT;   // 50000
  int E = in_sizes[1] / 2;       // 800000

  // workspace carve (~71 MB; z1 aliases fallback-only hidden_f32)
  char* w = (char*)d_ws;
  auto carve = [&](size_t bytes) -> void* {
    void* p = (void*)w;
    w += (bytes + 255) & ~(size_t)255;
    return p;
  };
  int*      flag      = (int*)     carve(4);
  int*      cnt       = (int*)     carve((size_t)N * 4);
  int*      row_start = (int*)     carve(((size_t)N + 1) * 4);
  int*      cursor    = (int*)     carve((size_t)N * 4);
  float*    dinv      = (float*)   carve((size_t)N * 4);
  int*      bsum      = (int*)     carve(64 * 4);
  int2*     csr       = (int2*)    carve((size_t)E * 8);
  unsigned* h_a       = (unsigned*)carve((size_t)N * 64 * 4);   // bf16x2 rows
  unsigned* h_b       = (unsigned*)carve((size_t)N * 64 * 4);
  unsigned* hid       = (unsigned*)carve((size_t)N * 64 * 4);   // final hidden bf16
  float*    hidden32  = (float*)   carve((size_t)N * NFEAT * 4); // fallback only
  unsigned short* z1  = (unsigned short*)hidden32;  // dead before gemm1 writes z1

  int nblk = (N + 1023) / 1024;   // 49

  k_detect64<<<1, 256, 0, stream>>>((const unsigned int*)d_in[1], flag);
  k_zero<<<(N + 255) / 256, 256, 0, stream>>>(cnt, N);
  k_count<<<(E + 255) / 256, 256, 0, stream>>>(ei32, ei64, E, N, cnt, flag);
  k_scan_a<<<nblk, 256, 0, stream>>>(cnt, bsum, N);
  k_scan_b<<<1, 64, 0, stream>>>(bsum, row_start, nblk, N);
  k_scan_c<<<nblk, 256, 0, stream>>>(cnt, bsum, row_start, cursor, dinv, N);
  k_fill<<<(E + 255) / 256, 256, 0, stream>>>(ei32, ei64, E, N, dinv, cursor, csr, flag);
  k_init_h<<<(N * 64 + 255) / 256, 256, 0, stream>>>(x, h_a, N * 64);

  // --- propagation: cooperative if it fits, else proven 10-launch fallback ---
  int maxActive = 0, numCU = 0, dev = 0;
  (void)hipGetDevice(&dev);
  (void)hipDeviceGetAttribute(&numCU, hipDeviceAttributeMultiprocessorCount, dev);
  hipError_t qerr = hipOccupancyMaxActiveBlocksPerMultiprocessor(
      &maxActive, k_prop_all, 256, 0);
  bool coop = (qerr == hipSuccess) && numCU > 0 &&
              ((long long)maxActive * numCU >= PBLOCKS);
  if (coop) {
    unsigned* ha = h_a; unsigned* hb = h_b; unsigned* hd = hid;
    const int* rs = row_start; const int2* cs = csr;
    const float* dv = dinv; const float* tp = temp; int n_ = N;
    void* args[] = { &ha, &hb, &hd, &rs, &cs, &dv, &tp, &n_ };
    hipError_t lerr = hipLaunchCooperativeKernel(
        (void*)k_prop_all, dim3(PBLOCKS), dim3(256), args, 0, stream);
    if (lerr != hipSuccess) coop = false;
  }
  if (!coop) {
    k_init_hid32<<<(N * 64 + 255) / 256, 256, 0, stream>>>(x, temp, hidden32, N * 64);
    unsigned* hc = h_a;
    unsigned* hn = h_b;
    for (int k = 0; k < KHOPS - 1; ++k) {
      k_prop<<<(N + 3) / 4, 256, 0, stream>>>(
          hc, hn, hidden32, row_start, csr, dinv, temp, k, N, 0);
      unsigned* t2 = hc; hc = hn; hn = t2;
    }
    k_prop<<<(N + 3) / 4, 256, 0, stream>>>(
        hc, hid, hidden32, row_start, csr, dinv, temp, KHOPS - 1, N, 1);
  }

  k_gemm1<<<dim3((N + 63) / 64, 2), 256, 0, stream>>>(
      (const unsigned short*)hid, W1, b1, z1, N);
  k_mlp2<<<(N + 63) / 64, 256, 0, stream>>>(z1, W2, b2, out, N);
}

// Round 8
// 611.308 us; speedup vs baseline: 3.9977x; 1.0016x over previous
//
#include <hip/hip_runtime.h>
#include <hip/hip_bf16.h>

// GPR-GNN forward on MI355X.
// R8: dropped cooperative path (R7 evidence: no speedup, unprofilable).
// CSR is now keyed (dst, src_block) with src blocks of 4096 nodes: every
// adjacency list is src-block-ordered, so all waves sweep source space in the
// same order -> instantaneous gather working set ~1MB (L2-resident per XCD).
// Prop kernel itself is the proven R5 structure (16-deep gather batches).

#define NFEAT 128
#define HID   256
#define NCLS  40
#define KHOPS 10
#define SBSHIFT 12               // 4096-node source blocks (1MB of bf16 h rows)

typedef __attribute__((ext_vector_type(8))) short short8;
typedef __attribute__((ext_vector_type(4))) float floatx4;

__device__ __forceinline__ float blo(unsigned g) { return __uint_as_float(g << 16); }
__device__ __forceinline__ float bhi(unsigned g) { return __uint_as_float(g & 0xffff0000u); }
__device__ __forceinline__ unsigned f2bf(float x) {          // RNE bf16 -> low 16
  unsigned u = __float_as_uint(x);
  return (u + 0x7fffu + ((u >> 16) & 1u)) >> 16;
}
__device__ __forceinline__ unsigned bpack(float a, float b) {
  return f2bf(a) | (f2bf(b) << 16);
}

// ---- storage probe: int64 values < 2^31 have all-zero odd 32-bit words ----
__global__ void k_detect64(const unsigned int* __restrict__ raw, int* __restrict__ flag) {
  __shared__ int any;
  int t = threadIdx.x;
  if (t == 0) any = 0;
  __syncthreads();
  if (raw[2 * t + 1] != 0u) any = 1;
  __syncthreads();
  if (t == 0) flag[0] = (any == 0) ? 1 : 0;   // 1 => int64 storage
}

__global__ void k_zero(int* __restrict__ p, int n) {
  int i = blockIdx.x * blockDim.x + threadIdx.x;
  if (i < n) p[i] = 0;
}

// count per (dst, src_block)
__global__ void k_count2(const int* __restrict__ ei32, const long long* __restrict__ ei64,
                         int E, int N, int NB, int* __restrict__ cnt2,
                         const int* __restrict__ flag) {
  int e = blockIdx.x * blockDim.x + threadIdx.x;
  if (e >= E) return;
  int src, dst;
  if (flag[0]) { src = (int)ei64[e]; dst = (int)ei64[(size_t)E + e]; }
  else         { src = ei32[e];      dst = ei32[(size_t)E + e]; }
  if ((unsigned)src >= (unsigned)N || (unsigned)dst >= (unsigned)N) return;
  atomicAdd(&cnt2[(size_t)dst * NB + (src >> SBSHIFT)], 1);
}

// ---- 3-level parallel exclusive scan over npair elements (tiles of 1024) ----
__global__ __launch_bounds__(256) void k_scan_a(
    const int* __restrict__ cnt, int* __restrict__ bsum, int n) {
  int t = threadIdx.x;
  int base = blockIdx.x * 1024 + t * 4;
  int s = 0;
  if (base + 3 < n) {
    int4 v = *(const int4*)(cnt + base);
    s = v.x + v.y + v.z + v.w;
  } else {
    #pragma unroll
    for (int j = 0; j < 4; ++j) if (base + j < n) s += cnt[base + j];
  }
  #pragma unroll
  for (int off = 1; off < 64; off <<= 1) s += __shfl_xor(s, off);
  __shared__ int ws[4];
  if ((t & 63) == 0) ws[t >> 6] = s;
  __syncthreads();
  if (t == 0) bsum[blockIdx.x] = ws[0] + ws[1] + ws[2] + ws[3];
}

// single 1024-thread block scans up to 1024 tile sums; writes sentinel S[npair]
__global__ void k_scan_mid(int* __restrict__ bsum, int* __restrict__ S,
                           int ntiles, int npair) {
  int t = threadIdx.x;
  int lane = t & 63, wid = t >> 6;
  int v = (t < ntiles) ? bsum[t] : 0;
  int x = v;
  #pragma unroll
  for (int off = 1; off < 64; off <<= 1) {
    int u = __shfl_up(x, off);
    if (lane >= off) x += u;
  }
  __shared__ int ws[16];
  if (lane == 63) ws[wid] = x;
  __syncthreads();
  if (wid == 0) {
    int s2 = (lane < 16) ? ws[lane] : 0;
    #pragma unroll
    for (int off = 1; off < 16; off <<= 1) {
      int u = __shfl_up(s2, off);
      if (lane >= off) s2 += u;
    }
    if (lane < 16) ws[lane] = s2;
  }
  __syncthreads();
  int woff = wid ? ws[wid - 1] : 0;
  if (t < ntiles) bsum[t] = x - v + woff;   // exclusive tile offsets
  if (t == 0) S[npair] = ws[15];            // grand total sentinel
}

__global__ __launch_bounds__(256) void k_scan_c(
    const int* __restrict__ cnt, const int* __restrict__ bsum,
    int* __restrict__ S, int* __restrict__ cursor, int n) {
  int t = threadIdx.x;
  int base = blockIdx.x * 1024 + t * 4;
  int v[4];
  if (base + 3 < n) {
    int4 q = *(const int4*)(cnt + base);
    v[0] = q.x; v[1] = q.y; v[2] = q.z; v[3] = q.w;
  } else {
    #pragma unroll
    for (int j = 0; j < 4; ++j) v[j] = (base + j < n) ? cnt[base + j] : 0;
  }
  int tsum = v[0] + v[1] + v[2] + v[3];
  int lane = t & 63, wv = t >> 6;
  int x = tsum;
  #pragma unroll
  for (int off = 1; off < 64; off <<= 1) {
    int u = __shfl_up(x, off);
    if (lane >= off) x += u;
  }
  __shared__ int ws[4];
  if (lane == 63) ws[wv] = x;
  __syncthreads();
  int woff = 0;
  #pragma unroll
  for (int j = 0; j < 4; ++j) if (j < wv) woff += ws[j];
  int run = x - tsum + woff + bsum[blockIdx.x];
  #pragma unroll
  for (int j = 0; j < 4; ++j) {
    int idx = base + j;
    if (idx < n) {
      S[idx] = run;
      cursor[idx] = run;
      run += v[j];
    }
  }
}

// dinv from row extents: deg(dst) = S[(dst+1)*NB] - S[dst*NB]
__global__ void k_dinv(const int* __restrict__ S, float* __restrict__ dinv,
                       int N, int NB) {
  int i = blockIdx.x * blockDim.x + threadIdx.x;
  if (i >= N) return;
  int deg = S[(size_t)(i + 1) * NB] - S[(size_t)i * NB];
  dinv[i] = rsqrtf((float)(deg + 1));
}

__global__ void k_fill2(const int* __restrict__ ei32, const long long* __restrict__ ei64,
                        int E, int N, int NB, const float* __restrict__ dinv,
                        int* __restrict__ cursor, int2* __restrict__ csr,
                        const int* __restrict__ flag) {
  int e = blockIdx.x * blockDim.x + threadIdx.x;
  if (e >= E) return;
  int src, dst;
  if (flag[0]) { src = (int)ei64[e]; dst = (int)ei64[(size_t)E + e]; }
  else         { src = ei32[e];      dst = ei32[(size_t)E + e]; }
  if ((unsigned)src >= (unsigned)N || (unsigned)dst >= (unsigned)N) return;
  int p = atomicAdd(&cursor[(size_t)dst * NB + (src >> SBSHIFT)], 1);
  float w = dinv[src] * dinv[dst];
  csr[p] = make_int2(src, __float_as_int(w));
}

// x (f32 row-major) -> h2 (bf16x2 packed, [node][64] uints)
__global__ void k_init_h(const float* __restrict__ x, unsigned* __restrict__ h2,
                         int total64) {
  int i = blockIdx.x * blockDim.x + threadIdx.x;
  if (i >= total64) return;
  float2 xv = ((const float2*)x)[i];
  h2[i] = bpack(xv.x, xv.y);
}

// hidden_f32 = temp[0] * x
__global__ void k_init_hid32(const float* __restrict__ x, const float* __restrict__ temp,
                             float* __restrict__ hidden, int total64) {
  int i = blockIdx.x * blockDim.x + threadIdx.x;
  if (i >= total64) return;
  float2 xv = ((const float2*)x)[i];
  float t0 = temp[0];
  ((float2*)hidden)[i] = make_float2(t0 * xv.x, t0 * xv.y);
}

// One wave per node; lane covers features 2f,2f+1 (256B row gathers, 16 deep).
// Adjacency lists are src-block-ordered -> all waves sweep sources in the same
// order -> L2-resident gather window. mode 0: write h_new bf16 + RMW f32
// hidden. mode 1 (final hop): write hid_bf16 = hidden + t*total into hnew2.
__global__ __launch_bounds__(256) void k_prop(
    const unsigned* __restrict__ h2, unsigned* __restrict__ hnew2,
    float* __restrict__ hidden,
    const int* __restrict__ S, int NB, const int2* __restrict__ csr,
    const float* __restrict__ dinv, const float* __restrict__ temp,
    int k, int N, int mode) {
  int wid = __builtin_amdgcn_readfirstlane(threadIdx.x >> 6);
  int lane = threadIdx.x & 63;
  int node = blockIdx.x * 4 + wid;           // uniform (SGPR) per wave
  if (node >= N) return;
  int s = S[(size_t)node * NB], en = S[(size_t)(node + 1) * NB];
  float accL = 0.f, accH = 0.f;
  for (int p = s; p < en; p += 16) {
    unsigned g[16];
    float wt[16];
    #pragma unroll
    for (int j = 0; j < 16; ++j) {
      int pj = p + j;
      int2 e = csr[pj < en ? pj : s];        // clamped tail: broadcast dummy
      wt[j] = (pj < en) ? __int_as_float(e.y) : 0.f;
      g[j] = h2[(size_t)e.x * 64 + lane];    // 256B row gather, 16 in flight
    }
    #pragma unroll
    for (int j = 0; j < 16; ++j) {
      accL += wt[j] * blo(g[j]);
      accH += wt[j] * bhi(g[j]);
    }
  }
  float di = dinv[node];
  unsigned gs = h2[(size_t)node * 64 + lane];
  float dd = di * di;
  accL += dd * blo(gs);                      // self-loop term
  accH += dd * bhi(gs);
  float tk = temp[k + 1];
  float2* hp = (float2*)(hidden + (size_t)node * NFEAT) + lane;
  float2 hv = *hp;
  hv.x += tk * accL;
  hv.y += tk * accH;
  if (mode == 0) {
    hnew2[(size_t)node * 64 + lane] = bpack(accL, accH);
    *hp = hv;
  } else {
    hnew2[(size_t)node * 64 + lane] = bpack(hv.x, hv.y);   // final hidden, bf16
  }
}

// hidden_bf16 (Mx128) @ W1 (128x256 f32) + b1, relu -> z1 (Mx256 bf16).
__global__ __launch_bounds__(256) void k_gemm1(
    const unsigned short* __restrict__ Ab, const float* __restrict__ W1,
    const float* __restrict__ b1, unsigned short* __restrict__ z1, int M) {
  __shared__ unsigned short As[64][136];    // m-major, k contig, +8 pad
  __shared__ unsigned short Bs[16][128][8]; // [k>>3][n][k&7]: frag = ds_read_b128
  int tid = threadIdx.x;
  int m0 = blockIdx.x * 64;
  int n0 = blockIdx.y * 128;
  for (int idx = tid; idx < 64 * 16; idx += 256) {
    int m = idx >> 4, c = idx & 15;
    int row = m0 + m; if (row >= M) row = M - 1;
    uint4 v = *(const uint4*)(Ab + (size_t)row * NFEAT + c * 8);
    *(uint4*)&As[m][c * 8] = v;
  }
  for (int idx = tid; idx < 128 * 128; idx += 256) {
    int k = idx >> 7, n = idx & 127;
    Bs[k >> 3][n][k & 7] = (unsigned short)f2bf(W1[(size_t)k * HID + n0 + n]);
  }
  __syncthreads();
  int lane = tid & 63;
  int q = lane >> 4, r16 = lane & 15;
  int nw = (tid >> 6) * 32;
  floatx4 acc[4][2] = {};
  #pragma unroll
  for (int step = 0; step < 4; ++step) {
    int k0 = step * 32;
    short8 a[4], b[2];
    #pragma unroll
    for (int i = 0; i < 4; ++i)
      a[i] = *(const short8*)&As[i * 16 + r16][k0 + q * 8];
    #pragma unroll
    for (int j = 0; j < 2; ++j)
      b[j] = *(const short8*)&Bs[step * 4 + q][nw + j * 16 + r16][0];
    #pragma unroll
    for (int i = 0; i < 4; ++i)
      #pragma unroll
      for (int j = 0; j < 2; ++j)
        acc[i][j] = __builtin_amdgcn_mfma_f32_16x16x32_bf16(a[i], b[j], acc[i][j], 0, 0, 0);
  }
  __syncthreads();
  unsigned short* Zs = &As[0][0];
  #pragma unroll
  for (int j = 0; j < 2; ++j) {
    int n = nw + j * 16 + r16;
    float bias = b1[n0 + n];
    #pragma unroll
    for (int i = 0; i < 4; ++i) {
      #pragma unroll
      for (int r = 0; r < 4; ++r) {
        int m = i * 16 + q * 4 + r;
        float v = fmaxf(acc[i][j][r] + bias, 0.f);
        Zs[m * 136 + n] = (unsigned short)f2bf(v);
      }
    }
  }
  __syncthreads();
  for (int idx = tid; idx < 64 * 16; idx += 256) {
    int m = idx >> 4, c = idx & 15;
    int row = m0 + m;
    if (row < M) {
      uint4 v = *(const uint4*)&Zs[m * 136 + c * 8];
      *(uint4*)(z1 + (size_t)row * HID + n0 + c * 8) = v;
    }
  }
}

// z1 (Mx256 bf16) @ W2 (256x40) + b2 -> log_softmax -> out f32. Block = 64 nodes.
__global__ __launch_bounds__(256) void k_mlp2(
    const unsigned short* __restrict__ z1, const float* __restrict__ W2,
    const float* __restrict__ b2, float* __restrict__ out, int N) {
  __shared__ __align__(16) float W2g[4][HID][12];  // [q][k][j<10]
  __shared__ __align__(16) float Zs[64][36];       // 32-k chunk
  int tid = threadIdx.x;
  int q = tid >> 6, lane = tid & 63;
  for (int idx = tid; idx < 4 * HID * 10; idx += 256) {
    int qq = idx / (HID * 10);
    int rem = idx - qq * (HID * 10);
    int k = rem / 10, j = rem - k * 10;
    W2g[qq][k][j] = W2[k * NCLS + qq * 10 + j];
  }
  int n0 = blockIdx.x * 64;
  float acc[10];
  #pragma unroll
  for (int j = 0; j < 10; ++j) acc[j] = b2[q * 10 + j];
  for (int kk = 0; kk < HID; kk += 32) {
    __syncthreads();
    {
      int nn = tid >> 2;
      int part = tid & 3;
      int gn = n0 + nn;
      uint4 v = make_uint4(0u, 0u, 0u, 0u);
      if (gn < N) v = *(const uint4*)&z1[(size_t)gn * HID + kk + part * 8];
      float4 f0 = make_float4(blo(v.x), bhi(v.x), blo(v.y), bhi(v.y));
      float4 f1 = make_float4(blo(v.z), bhi(v.z), blo(v.w), bhi(v.w));
      *(float4*)&Zs[nn][part * 8] = f0;
      *(float4*)&Zs[nn][part * 8 + 4] = f1;
    }
    __syncthreads();
    #pragma unroll
    for (int k4 = 0; k4 < 32; k4 += 4) {
      float4 zv = *(const float4*)&Zs[lane][k4];
      float zz[4] = {zv.x, zv.y, zv.z, zv.w};
      #pragma unroll
      for (int t = 0; t < 4; ++t) {
        int k = kk + k4 + t;
        float4 w0 = *(const float4*)&W2g[q][k][0];
        float4 w1 = *(const float4*)&W2g[q][k][4];
        float2 w2 = *(const float2*)&W2g[q][k][8];
        acc[0] += zz[t] * w0.x;  acc[1] += zz[t] * w0.y;
        acc[2] += zz[t] * w0.z;  acc[3] += zz[t] * w0.w;
        acc[4] += zz[t] * w1.x;  acc[5] += zz[t] * w1.y;
        acc[6] += zz[t] * w1.z;  acc[7] += zz[t] * w1.w;
        acc[8] += zz[t] * w2.x;  acc[9] += zz[t] * w2.y;
      }
    }
  }
  __syncthreads();
  float* logits = &W2g[0][0][0];
  #pragma unroll
  for (int j = 0; j < 10; ++j) logits[lane * NCLS + q * 10 + j] = acc[j];
  __syncthreads();
  int nl = tid >> 2;
  int r = tid & 3;
  const float* lg = &logits[nl * NCLS + r * 10];
  float l10[10];
  float m = -3.4e38f;
  #pragma unroll
  for (int j = 0; j < 10; ++j) { l10[j] = lg[j]; m = fmaxf(m, l10[j]); }
  m = fmaxf(m, __shfl_xor(m, 1));
  m = fmaxf(m, __shfl_xor(m, 2));
  float s = 0.f;
  #pragma unroll
  for (int j = 0; j < 10; ++j) s += __expf(l10[j] - m);
  s += __shfl_xor(s, 1);
  s += __shfl_xor(s, 2);
  float lse = m + __logf(s);
  int gnode = n0 + nl;
  if (gnode < N) {
    #pragma unroll
    for (int j = 0; j < 10; ++j) out[(size_t)gnode * NCLS + r * 10 + j] = l10[j] - lse;
  }
}

extern "C" void kernel_launch(void* const* d_in, const int* in_sizes, int n_in,
                              void* d_out, int out_size, void* d_ws, size_t ws_size,
                              hipStream_t stream) {
  const float*     x    = (const float*)d_in[0];
  const int*       ei32 = (const int*)d_in[1];
  const long long* ei64 = (const long long*)d_in[1];
  const float*     temp = (const float*)d_in[2];
  const float*     W1   = (const float*)d_in[3];
  const float*     b1   = (const float*)d_in[4];
  const float*     W2   = (const float*)d_in[5];
  const float*     b2   = (const float*)d_in[6];
  float* out = (float*)d_out;

  int N = in_sizes[0] / NFEAT;   // 50000
  int E = in_sizes[1] / 2;       // 800000
  int NB = ((N - 1) >> SBSHIFT) + 1;   // 13 source blocks
  int NPAIR = N * NB;                  // 650000 (dst, blk) cells

  // workspace carve (~90 MB)
  char* w = (char*)d_ws;
  auto carve = [&](size_t bytes) -> void* {
    void* p = (void*)w;
    w += (bytes + 255) & ~(size_t)255;
    return p;
  };
  int*      flag      = (int*)     carve(4);
  int*      cnt2      = (int*)     carve((size_t)NPAIR * 4);
  int*      S         = (int*)     carve(((size_t)NPAIR + 1) * 4);
  int*      cursor2   = (int*)     carve((size_t)NPAIR * 4);
  float*    dinv      = (float*)   carve((size_t)N * 4);
  int*      bsum      = (int*)     carve(1024 * 4);
  int2*     csr       = (int2*)    carve((size_t)E * 8);
  unsigned* h_a       = (unsigned*)carve((size_t)N * 64 * 4);   // bf16x2 rows
  unsigned* h_b       = (unsigned*)carve((size_t)N * 64 * 4);
  unsigned* hid       = (unsigned*)carve((size_t)N * 64 * 4);   // final hidden bf16
  float*    hidden32  = (float*)   carve((size_t)N * NFEAT * 4);
  unsigned short* z1  = (unsigned short*)hidden32;  // dead before gemm1 writes z1

  int ntiles = (NPAIR + 1023) / 1024;   // 635 <= 1024

  k_detect64<<<1, 256, 0, stream>>>((const unsigned int*)d_in[1], flag);
  k_zero<<<(NPAIR + 255) / 256, 256, 0, stream>>>(cnt2, NPAIR);
  k_count2<<<(E + 255) / 256, 256, 0, stream>>>(ei32, ei64, E, N, NB, cnt2, flag);
  k_scan_a<<<ntiles, 256, 0, stream>>>(cnt2, bsum, NPAIR);
  k_scan_mid<<<1, 1024, 0, stream>>>(bsum, S, ntiles, NPAIR);
  k_scan_c<<<ntiles, 256, 0, stream>>>(cnt2, bsum, S, cursor2, NPAIR);
  k_dinv<<<(N + 255) / 256, 256, 0, stream>>>(S, dinv, N, NB);
  k_fill2<<<(E + 255) / 256, 256, 0, stream>>>(ei32, ei64, E, N, NB, dinv,
                                               cursor2, csr, flag);
  k_init_h<<<(N * 64 + 255) / 256, 256, 0, stream>>>(x, h_a, N * 64);
  k_init_hid32<<<(N * 64 + 255) / 256, 256, 0, stream>>>(x, temp, hidden32, N * 64);

  unsigned* hc = h_a;
  unsigned* hn = h_b;
  for (int k = 0; k < KHOPS - 1; ++k) {
    k_prop<<<(N + 3) / 4, 256, 0, stream>>>(
        hc, hn, hidden32, S, NB, csr, dinv, temp, k, N, 0);
    unsigned* t2 = hc; hc = hn; hn = t2;
  }
  k_prop<<<(N + 3) / 4, 256, 0, stream>>>(
      hc, hid, hidden32, S, NB, csr, dinv, temp, KHOPS - 1, N, 1);

  k_gemm1<<<dim3((N + 63) / 64, 2), 256, 0, stream>>>(
      (const unsigned short*)hid, W1, b1, z1, N);
  k_mlp2<<<(N + 63) / 64, 256, 0, stream>>>(z1, W2, b2, out, N);
}

// Round 9
// 608.971 us; speedup vs baseline: 4.0130x; 1.0038x over previous
//
#include <hip/hip_runtime.h>
#include <hip/hip_bf16.h>

// GPR-GNN forward on MI355X.
// R9: (a) mlp2 rewritten as LDS-free MFMA GEMM + register log-softmax (R8
//     evidence: 57KB LDS -> 13% occupancy, 45.6us at 7x roofline).
//     (b) prop gathers consolidated to dwordx4 (4 edges/instruction, same bytes
//     same depth) -- discriminating test: issue-rate-bound vs L3-service-bound.
//     (c) CSR build reverted to plain dst keying (R8 block-keying was neutral);
//     init kernels fused.

#define NFEAT 128
#define HID   256
#define NCLS  40
#define KHOPS 10

typedef __attribute__((ext_vector_type(8))) short short8;
typedef __attribute__((ext_vector_type(4))) float floatx4;

__device__ __forceinline__ float blo(unsigned g) { return __uint_as_float(g << 16); }
__device__ __forceinline__ float bhi(unsigned g) { return __uint_as_float(g & 0xffff0000u); }
__device__ __forceinline__ unsigned f2bf(float x) {          // RNE bf16 -> low 16
  unsigned u = __float_as_uint(x);
  return (u + 0x7fffu + ((u >> 16) & 1u)) >> 16;
}
__device__ __forceinline__ unsigned bpack(float a, float b) {
  return f2bf(a) | (f2bf(b) << 16);
}

// ---- storage probe: int64 values < 2^31 have all-zero odd 32-bit words ----
__global__ void k_detect64(const unsigned int* __restrict__ raw, int* __restrict__ flag) {
  __shared__ int any;
  int t = threadIdx.x;
  if (t == 0) any = 0;
  __syncthreads();
  if (raw[2 * t + 1] != 0u) any = 1;
  __syncthreads();
  if (t == 0) flag[0] = (any == 0) ? 1 : 0;   // 1 => int64 storage
}

__global__ void k_zero(int* __restrict__ p, int n) {
  int i = blockIdx.x * blockDim.x + threadIdx.x;
  if (i < n) p[i] = 0;
}

__global__ void k_count(const int* __restrict__ ei32, const long long* __restrict__ ei64,
                        int E, int N, int* __restrict__ cnt, const int* __restrict__ flag) {
  int e = blockIdx.x * blockDim.x + threadIdx.x;
  if (e >= E) return;
  int dst = flag[0] ? (int)ei64[(size_t)E + e] : ei32[(size_t)E + e];
  if ((unsigned)dst < (unsigned)N) atomicAdd(&cnt[dst], 1);
}

// ---- 3-level parallel exclusive scan (tiles of 1024) ----
__global__ __launch_bounds__(256) void k_scan_a(
    const int* __restrict__ cnt, int* __restrict__ bsum, int n) {
  int t = threadIdx.x;
  int base = blockIdx.x * 1024 + t * 4;
  int s = 0;
  if (base + 3 < n) {
    int4 v = *(const int4*)(cnt + base);
    s = v.x + v.y + v.z + v.w;
  } else {
    #pragma unroll
    for (int j = 0; j < 4; ++j) if (base + j < n) s += cnt[base + j];
  }
  #pragma unroll
  for (int off = 1; off < 64; off <<= 1) s += __shfl_xor(s, off);
  __shared__ int ws[4];
  if ((t & 63) == 0) ws[t >> 6] = s;
  __syncthreads();
  if (t == 0) bsum[blockIdx.x] = ws[0] + ws[1] + ws[2] + ws[3];
}

__global__ void k_scan_mid(int* __restrict__ bsum, int* __restrict__ S,
                           int ntiles, int n) {
  int t = threadIdx.x;
  int lane = t & 63, wid = t >> 6;
  int v = (t < ntiles) ? bsum[t] : 0;
  int x = v;
  #pragma unroll
  for (int off = 1; off < 64; off <<= 1) {
    int u = __shfl_up(x, off);
    if (lane >= off) x += u;
  }
  __shared__ int ws[16];
  if (lane == 63) ws[wid] = x;
  __syncthreads();
  if (wid == 0) {
    int s2 = (lane < 16) ? ws[lane] : 0;
    #pragma unroll
    for (int off = 1; off < 16; off <<= 1) {
      int u = __shfl_up(s2, off);
      if (lane >= off) s2 += u;
    }
    if (lane < 16) ws[lane] = s2;
  }
  __syncthreads();
  int woff = wid ? ws[wid - 1] : 0;
  if (t < ntiles) bsum[t] = x - v + woff;   // exclusive tile offsets
  if (t == 0) S[n] = ws[15];                // grand total sentinel
}

__global__ __launch_bounds__(256) void k_scan_c(
    const int* __restrict__ cnt, const int* __restrict__ bsum,
    int* __restrict__ S, int* __restrict__ cursor, int n) {
  int t = threadIdx.x;
  int base = blockIdx.x * 1024 + t * 4;
  int v[4];
  if (base + 3 < n) {
    int4 q = *(const int4*)(cnt + base);
    v[0] = q.x; v[1] = q.y; v[2] = q.z; v[3] = q.w;
  } else {
    #pragma unroll
    for (int j = 0; j < 4; ++j) v[j] = (base + j < n) ? cnt[base + j] : 0;
  }
  int tsum = v[0] + v[1] + v[2] + v[3];
  int lane = t & 63, wv = t >> 6;
  int x = tsum;
  #pragma unroll
  for (int off = 1; off < 64; off <<= 1) {
    int u = __shfl_up(x, off);
    if (lane >= off) x += u;
  }
  __shared__ int ws[4];
  if (lane == 63) ws[wv] = x;
  __syncthreads();
  int woff = 0;
  #pragma unroll
  for (int j = 0; j < 4; ++j) if (j < wv) woff += ws[j];
  int run = x - tsum + woff + bsum[blockIdx.x];
  #pragma unroll
  for (int j = 0; j < 4; ++j) {
    int idx = base + j;
    if (idx < n) {
      S[idx] = run;
      cursor[idx] = run;
      run += v[j];
    }
  }
}

// dinv from row extents: deg(i) = S[i+1] - S[i]
__global__ void k_dinv(const int* __restrict__ S, float* __restrict__ dinv, int N) {
  int i = blockIdx.x * blockDim.x + threadIdx.x;
  if (i >= N) return;
  int deg = S[i + 1] - S[i];
  dinv[i] = rsqrtf((float)(deg + 1));
}

__global__ void k_fill(const int* __restrict__ ei32, const long long* __restrict__ ei64,
                       int E, int N, const float* __restrict__ dinv,
                       int* __restrict__ cursor, int2* __restrict__ csr,
                       const int* __restrict__ flag) {
  int e = blockIdx.x * blockDim.x + threadIdx.x;
  if (e >= E) return;
  int src, dst;
  if (flag[0]) { src = (int)ei64[e]; dst = (int)ei64[(size_t)E + e]; }
  else         { src = ei32[e];      dst = ei32[(size_t)E + e]; }
  if ((unsigned)src >= (unsigned)N || (unsigned)dst >= (unsigned)N) return;
  int p = atomicAdd(&cursor[dst], 1);
  float w = dinv[src] * dinv[dst];
  csr[p] = make_int2(src, __float_as_int(w));
}

// fused init: x -> h2 (bf16x2) and hidden32 = temp[0]*x  (single x read)
__global__ void k_init(const float* __restrict__ x, const float* __restrict__ temp,
                       unsigned* __restrict__ h2, float* __restrict__ hidden,
                       int total64) {
  int i = blockIdx.x * blockDim.x + threadIdx.x;
  if (i >= total64) return;
  float2 xv = ((const float2*)x)[i];
  h2[i] = bpack(xv.x, xv.y);
  float t0 = temp[0];
  ((float2*)hidden)[i] = make_float2(t0 * xv.x, t0 * xv.y);
}

// One wave per node. lane = e*16+g: 4 edges per dwordx4 instruction (lane g
// carries features 8g..8g+7 of edge e's row; lane's own csr entry gives its
// weight). 16 edges in flight in 4 vmem instrs (same bytes/depth as R5, 1/4
// the instruction count). Final cross-subgroup shfl-reduce; epilogue on lanes
// 0-15. mode 0: write h_new bf16 + RMW f32 hidden; mode 1: write final bf16
// hidden (= hidden32 + t*total) into hnew2.
__global__ __launch_bounds__(256) void k_prop(
    const unsigned* __restrict__ h2, unsigned* __restrict__ hnew2,
    float* __restrict__ hidden,
    const int* __restrict__ S, const int2* __restrict__ csr,
    const float* __restrict__ dinv, const float* __restrict__ temp,
    int k, int N, int mode) {
  int wid = __builtin_amdgcn_readfirstlane(threadIdx.x >> 6);
  int lane = threadIdx.x & 63;
  int node = blockIdx.x * 4 + wid;           // uniform (SGPR) per wave
  if (node >= N) return;
  int g = lane & 15;                         // feature group: feats 8g..8g+7
  int e = lane >> 4;                         // edge subgroup 0..3
  int s = S[node], en = S[node + 1];
  float acc[8] = {0.f, 0.f, 0.f, 0.f, 0.f, 0.f, 0.f, 0.f};
  for (int p = s; p < en; p += 16) {
    uint4 gd[4];
    float wt[4];
    #pragma unroll
    for (int t = 0; t < 4; ++t) {
      int pj = p + t * 4 + e;
      int2 ed = csr[pj < en ? pj : s];       // per-lane clamp: dummy, w=0
      wt[t] = (pj < en) ? __int_as_float(ed.y) : 0.f;
      gd[t] = *(const uint4*)(h2 + (size_t)ed.x * 64 + g * 4);  // 16B of row
    }
    #pragma unroll
    for (int t = 0; t < 4; ++t) {
      const unsigned* gu = (const unsigned*)&gd[t];
      #pragma unroll
      for (int u = 0; u < 4; ++u) {
        acc[u * 2]     += wt[t] * blo(gu[u]);
        acc[u * 2 + 1] += wt[t] * bhi(gu[u]);
      }
    }
  }
  #pragma unroll
  for (int u = 0; u < 8; ++u) {              // reduce over the 4 edge subgroups
    acc[u] += __shfl_xor(acc[u], 16);
    acc[u] += __shfl_xor(acc[u], 32);
  }
  if (e == 0) {                              // lanes 0-15 own the epilogue
    float di = dinv[node];
    float dd = di * di;
    uint4 gs = *(const uint4*)(h2 + (size_t)node * 64 + g * 4);
    const unsigned* su = (const unsigned*)&gs;
    #pragma unroll
    for (int u = 0; u < 4; ++u) {
      acc[u * 2]     += dd * blo(su[u]);     // self-loop term
      acc[u * 2 + 1] += dd * bhi(su[u]);
    }
    float tk = temp[k + 1];
    float4* hp = (float4*)(hidden + (size_t)node * NFEAT + g * 8);
    float4 h0 = hp[0], h1 = hp[1];
    h0.x += tk * acc[0];  h0.y += tk * acc[1];
    h0.z += tk * acc[2];  h0.w += tk * acc[3];
    h1.x += tk * acc[4];  h1.y += tk * acc[5];
    h1.z += tk * acc[6];  h1.w += tk * acc[7];
    uint4 pk;
    if (mode == 0) {
      pk.x = bpack(acc[0], acc[1]);  pk.y = bpack(acc[2], acc[3]);
      pk.z = bpack(acc[4], acc[5]);  pk.w = bpack(acc[6], acc[7]);
      *(uint4*)(hnew2 + (size_t)node * 64 + g * 4) = pk;
      hp[0] = h0;  hp[1] = h1;
    } else {
      pk.x = bpack(h0.x, h0.y);  pk.y = bpack(h0.z, h0.w);
      pk.z = bpack(h1.x, h1.y);  pk.w = bpack(h1.z, h1.w);
      *(uint4*)(hnew2 + (size_t)node * 64 + g * 4) = pk;
    }
  }
}

// hidden_bf16 (Mx128) @ W1 (128x256 f32) + b1, relu -> z1 (Mx256 bf16).
__global__ __launch_bounds__(256) void k_gemm1(
    const unsigned short* __restrict__ Ab, const float* __restrict__ W1,
    const float* __restrict__ b1, unsigned short* __restrict__ z1, int M) {
  __shared__ unsigned short As[64][136];    // m-major, k contig, +8 pad
  __shared__ unsigned short Bs[16][128][8]; // [k>>3][n][k&7]: frag = ds_read_b128
  int tid = threadIdx.x;
  int m0 = blockIdx.x * 64;
  int n0 = blockIdx.y * 128;
  for (int idx = tid; idx < 64 * 16; idx += 256) {
    int m = idx >> 4, c = idx & 15;
    int row = m0 + m; if (row >= M) row = M - 1;
    uint4 v = *(const uint4*)(Ab + (size_t)row * NFEAT + c * 8);
    *(uint4*)&As[m][c * 8] = v;
  }
  for (int idx = tid; idx < 128 * 128; idx += 256) {
    int k = idx >> 7, n = idx & 127;
    Bs[k >> 3][n][k & 7] = (unsigned short)f2bf(W1[(size_t)k * HID + n0 + n]);
  }
  __syncthreads();
  int lane = tid & 63;
  int q = lane >> 4, r16 = lane & 15;
  int nw = (tid >> 6) * 32;
  floatx4 acc[4][2] = {};
  #pragma unroll
  for (int step = 0; step < 4; ++step) {
    int k0 = step * 32;
    short8 a[4], b[2];
    #pragma unroll
    for (int i = 0; i < 4; ++i)
      a[i] = *(const short8*)&As[i * 16 + r16][k0 + q * 8];
    #pragma unroll
    for (int j = 0; j < 2; ++j)
      b[j] = *(const short8*)&Bs[step * 4 + q][nw + j * 16 + r16][0];
    #pragma unroll
    for (int i = 0; i < 4; ++i)
      #pragma unroll
      for (int j = 0; j < 2; ++j)
        acc[i][j] = __builtin_amdgcn_mfma_f32_16x16x32_bf16(a[i], b[j], acc[i][j], 0, 0, 0);
  }
  __syncthreads();
  unsigned short* Zs = &As[0][0];
  #pragma unroll
  for (int j = 0; j < 2; ++j) {
    int n = nw + j * 16 + r16;
    float bias = b1[n0 + n];
    #pragma unroll
    for (int i = 0; i < 4; ++i) {
      #pragma unroll
      for (int r = 0; r < 4; ++r) {
        int m = i * 16 + q * 4 + r;
        float v = fmaxf(acc[i][j][r] + bias, 0.f);
        Zs[m * 136 + n] = (unsigned short)f2bf(v);
      }
    }
  }
  __syncthreads();
  for (int idx = tid; idx < 64 * 16; idx += 256) {
    int m = idx >> 4, c = idx & 15;
    int row = m0 + m;
    if (row < M) {
      uint4 v = *(const uint4*)&Zs[m * 136 + c * 8];
      *(uint4*)(z1 + (size_t)row * HID + n0 + c * 8) = v;
    }
  }
}

// W2 (256x40 f32) -> W2t bf16 [48][256] (n-major, k-contig; n>=40 zero-padded)
__global__ void k_w2prep(const float* __restrict__ W2, unsigned short* __restrict__ W2t) {
  int i = blockIdx.x * blockDim.x + threadIdx.x;
  if (i >= 48 * 256) return;
  int n = i >> 8, k = i & 255;
  W2t[n * 256 + k] = (n < NCLS) ? (unsigned short)f2bf(W2[(size_t)k * NCLS + n]) : 0;
}

// z1 (Mx256 bf16) @ W2t + b2 -> log_softmax -> out f32.
// LDS-free MFMA: block = 4 waves x 16 nodes; 3 n-tiles (48 cols, 40 valid).
// C layout: col=lane&15 (class), row=q*4+reg (node). Softmax via 16-lane shfl.
__global__ __launch_bounds__(256) void k_mlp2(
    const unsigned short* __restrict__ z1, const unsigned short* __restrict__ W2t,
    const float* __restrict__ b2, float* __restrict__ out, int N) {
  int tid = threadIdx.x;
  int lane = tid & 63;
  int wv = tid >> 6;
  int node0 = blockIdx.x * 64 + wv * 16;
  int q = lane >> 4, m = lane & 15;
  int arow = node0 + m; if (arow >= N) arow = N - 1;
  const unsigned short* aptr = z1 + (size_t)arow * HID + q * 8;
  const unsigned short* bptr = W2t + (size_t)m * HID + q * 8;   // + j*16*HID
  floatx4 acc[3] = {};
  #pragma unroll
  for (int step = 0; step < 8; ++step) {     // K = 8 x 32
    short8 a = *(const short8*)(aptr + step * 32);
    #pragma unroll
    for (int j = 0; j < 3; ++j) {
      short8 b = *(const short8*)(bptr + (size_t)j * 16 * HID + step * 32);
      acc[j] = __builtin_amdgcn_mfma_f32_16x16x32_bf16(a, b, acc[j], 0, 0, 0);
    }
  }
  int c = m;                                  // class within tile = col = lane&15
  bool v2 = (c < NCLS - 32);                  // c+32 < 40
  float bb0 = b2[c], bb1 = b2[c + 16];
  float bb2 = v2 ? b2[c + 32] : 0.f;
  #pragma unroll
  for (int r = 0; r < 4; ++r) {
    int node = node0 + q * 4 + r;
    float l0 = acc[0][r] + bb0;
    float l1 = acc[1][r] + bb1;
    float l2 = v2 ? (acc[2][r] + bb2) : -3.4e38f;
    float mx = fmaxf(fmaxf(l0, l1), l2);
    #pragma unroll
    for (int off = 1; off < 16; off <<= 1) mx = fmaxf(mx, __shfl_xor(mx, off));
    float sm = __expf(l0 - mx) + __expf(l1 - mx) + (v2 ? __expf(l2 - mx) : 0.f);
    #pragma unroll
    for (int off = 1; off < 16; off <<= 1) sm += __shfl_xor(sm, off);
    float lse = mx + __logf(sm);
    if (node < N) {
      float* op = out + (size_t)node * NCLS + c;
      op[0] = l0 - lse;
      op[16] = l1 - lse;
      if (v2) op[32] = l2 - lse;
    }
  }
}

extern "C" void kernel_launch(void* const* d_in, const int* in_sizes, int n_in,
                              void* d_out, int out_size, void* d_ws, size_t ws_size,
                              hipStream_t stream) {
  const float*     x    = (const float*)d_in[0];
  const int*       ei32 = (const int*)d_in[1];
  const long long* ei64 = (const long long*)d_in[1];
  const float*     temp = (const float*)d_in[2];
  const float*     W1   = (const float*)d_in[3];
  const float*     b1   = (const float*)d_in[4];
  const float*     W2   = (const float*)d_in[5];
  const float*     b2   = (const float*)d_in[6];
  float* out = (float*)d_out;

  int N = in_sizes[0] / NFEAT;   // 50000
  int E = in_sizes[1] / 2;       // 800000

  // workspace carve (~71 MB)
  char* w = (char*)d_ws;
  auto carve = [&](size_t bytes) -> void* {
    void* p = (void*)w;
    w += (bytes + 255) & ~(size_t)255;
    return p;
  };
  int*      flag      = (int*)     carve(4);
  int*      cnt       = (int*)     carve((size_t)N * 4);
  int*      S         = (int*)     carve(((size_t)N + 1) * 4);
  int*      cursor    = (int*)     carve((size_t)N * 4);
  float*    dinv      = (float*)   carve((size_t)N * 4);
  int*      bsum      = (int*)     carve(1024 * 4);
  unsigned short* W2t = (unsigned short*)carve(48 * 256 * 2);
  int2*     csr       = (int2*)    carve((size_t)E * 8);
  unsigned* h_a       = (unsigned*)carve((size_t)N * 64 * 4);   // bf16x2 rows
  unsigned* h_b       = (unsigned*)carve((size_t)N * 64 * 4);
  unsigned* hid       = (unsigned*)carve((size_t)N * 64 * 4);   // final hidden bf16
  float*    hidden32  = (float*)   carve((size_t)N * NFEAT * 4);
  unsigned short* z1  = (unsigned short*)hidden32;  // dead before gemm1 writes z1

  int ntiles = (N + 1023) / 1024;   // 49

  k_detect64<<<1, 256, 0, stream>>>((const unsigned int*)d_in[1], flag);
  k_zero<<<(N + 255) / 256, 256, 0, stream>>>(cnt, N);
  k_count<<<(E + 255) / 256, 256, 0, stream>>>(ei32, ei64, E, N, cnt, flag);
  k_scan_a<<<ntiles, 256, 0, stream>>>(cnt, bsum, N);
  k_scan_mid<<<1, 1024, 0, stream>>>(bsum, S, ntiles, N);
  k_scan_c<<<ntiles, 256, 0, stream>>>(cnt, bsum, S, cursor, N);
  k_dinv<<<(N + 255) / 256, 256, 0, stream>>>(S, dinv, N);
  k_fill<<<(E + 255) / 256, 256, 0, stream>>>(ei32, ei64, E, N, dinv, cursor, csr, flag);
  k_init<<<(N * 64 + 255) / 256, 256, 0, stream>>>(x, temp, h_a, hidden32, N * 64);
  k_w2prep<<<48, 256, 0, stream>>>(W2, W2t);

  unsigned* hc = h_a;
  unsigned* hn = h_b;
  for (int k = 0; k < KHOPS - 1; ++k) {
    k_prop<<<(N + 3) / 4, 256, 0, stream>>>(
        hc, hn, hidden32, S, csr, dinv, temp, k, N, 0);
    unsigned* t2 = hc; hc = hn; hn = t2;
  }
  k_prop<<<(N + 3) / 4, 256, 0, stream>>>(
      hc, hid, hidden32, S, csr, dinv, temp, KHOPS - 1, N, 1);

  k_gemm1<<<dim3((N + 63) / 64, 2), 256, 0, stream>>>(
      (const unsigned short*)hid, W1, b1, z1, N);
  k_mlp2<<<(N + 63) / 64, 256, 0, stream>>>(z1, W2t, b2, out, N);
}